// Round 1
// baseline (2266.015 us; speedup 1.0000x reference)
//
#include <hip/hip_runtime.h>
#include <math.h>
#include <float.h>

#define B_Q   1024
#define N_M   50000
#define DIM   256
#define ATOMS 200
#define KSEL  8
#define NCHUNK 25
#define CHUNK  2000      // N_M / NCHUNK exactly
#define QT     32        // queries per score block
#define MT     128       // memories per inner tile
#define T16    16        // candidates kept per (query, chunk)

// ---------------------------------------------------------------------------
// Transform: H = to_poincare(X @ W + b), fp64 accumulation for fidelity.
// Block = 256 threads = 4 waves; each wave owns 8 rows; lane owns 4 columns.
// ---------------------------------------------------------------------------
__global__ __launch_bounds__(256) void transform_kernel(
    const float* __restrict__ X, int nrows,
    const float* __restrict__ W, const float* __restrict__ bvec,
    float* __restrict__ H, float* __restrict__ sq)
{
  const int t  = threadIdx.x;
  const int tx = t & 63;
  const int ty = t >> 6;
  const int row0 = blockIdx.x * 32 + ty * 8;

  const float* xp[8];
#pragma unroll
  for (int r = 0; r < 8; ++r) {
    int row = row0 + r;
    if (row >= nrows) row = nrows - 1;   // clamp; stores guarded below
    xp[r] = X + (size_t)row * DIM;
  }

  double acc[8][4];
#pragma unroll
  for (int r = 0; r < 8; ++r)
#pragma unroll
    for (int j = 0; j < 4; ++j) acc[r][j] = 0.0;

  for (int d = 0; d < DIM; d += 4) {
    float w[4][4];
#pragma unroll
    for (int dd = 0; dd < 4; ++dd) {
      const float* wr = W + (size_t)(d + dd) * DIM + tx;
      w[dd][0] = wr[0]; w[dd][1] = wr[64]; w[dd][2] = wr[128]; w[dd][3] = wr[192];
    }
#pragma unroll
    for (int r = 0; r < 8; ++r) {
      const float4 x4 = *(const float4*)(xp[r] + d);
#pragma unroll
      for (int j = 0; j < 4; ++j) {
        acc[r][j] += (double)x4.x * (double)w[0][j];
        acc[r][j] += (double)x4.y * (double)w[1][j];
        acc[r][j] += (double)x4.z * (double)w[2][j];
        acc[r][j] += (double)x4.w * (double)w[3][j];
      }
    }
  }

  float bv[4];
  bv[0] = bvec[tx]; bv[1] = bvec[tx + 64]; bv[2] = bvec[tx + 128]; bv[3] = bvec[tx + 192];

#pragma unroll
  for (int r = 0; r < 8; ++r) {
    const int row = row0 + r;
    if (row < nrows) {                   // wave-uniform branch (row uniform per wave)
      double h[4], nsq = 0.0;
#pragma unroll
      for (int j = 0; j < 4; ++j) { h[j] = tanh(acc[r][j] + (double)bv[j]); nsq += h[j] * h[j]; }
#pragma unroll
      for (int off = 1; off < 64; off <<= 1) nsq += __shfl_xor(nsq, off);
      const double nrm = sqrt(nsq);
      const double scl = (nrm > 0.95) ? (0.95 / nrm) : 1.0;
      float u[4]; double ysq = 0.0;
#pragma unroll
      for (int j = 0; j < 4; ++j) { u[j] = (float)(h[j] * scl); ysq += (double)u[j] * (double)u[j]; }
#pragma unroll
      for (int off = 1; off < 64; off <<= 1) ysq += __shfl_xor(ysq, off);
      float* Hr = H + (size_t)row * DIM;
      Hr[tx] = u[0]; Hr[tx + 64] = u[1]; Hr[tx + 128] = u[2]; Hr[tx + 192] = u[3];
      if (tx == 0) sq[row] = (float)ysq;
    }
  }
}

// ---------------------------------------------------------------------------
// Score: per (query-tile, memory-chunk) block, fp32 dots via LDS outer-product
// tiling, per-query register-resident running top-16 (smallest t-score).
// t = diff_sq / (denom + 1e-8) is monotone in the hyperbolic distance.
// ---------------------------------------------------------------------------
__global__ __launch_bounds__(256) void score_kernel(
    const float* __restrict__ Hq, const float* __restrict__ Hm,
    const float* __restrict__ xsq, const float* __restrict__ ysq,
    float* __restrict__ cand_s, int* __restrict__ cand_i)
{
  __shared__ float Qt[DIM * QT];   // [d][q], 32 KB
  __shared__ float U[4224];        // union: Mt[32][132] during compute, Sc[32][129] after
  __shared__ float ysh[MT];
  __shared__ float xsh[QT];

  const int t = threadIdx.x;
  const int q0 = blockIdx.x * QT;
  const int mbase = blockIdx.y * CHUNK;

  // Stage Q tile transposed: Qt[d][q]
#pragma unroll
  for (int p = 0; p < 8; ++p) {
    int i = t + 256 * p;
    int dql = i & 7, q = (i >> 3) & 31, dqh = i >> 8;
    int d = 4 * (dql + 8 * dqh);
    float4 v = *(const float4*)(Hq + (size_t)(q0 + q) * DIM + d);
    Qt[(d + 0) * QT + q] = v.x; Qt[(d + 1) * QT + q] = v.y;
    Qt[(d + 2) * QT + q] = v.z; Qt[(d + 3) * QT + q] = v.w;
  }
  if (t < QT) xsh[t] = xsq[q0 + t];

  const int qi = t & 7;        // 8 groups of 4 queries
  const int mi = t >> 3;       // 32 groups of 4 memories

  float topS[T16]; int topI[T16];
  float curMax = FLT_MAX; int curArg = 0;
#pragma unroll
  for (int j = 0; j < T16; ++j) { topS[j] = FLT_MAX; topI[j] = 0; }

  for (int mt = 0; mt < (CHUNK + MT - 1) / MT; ++mt) {
    const int m0 = mt * MT;
    __syncthreads();                       // previous scan done before U/ysh reuse
    if (t < MT) {
      int mm = m0 + t;
      ysh[t] = (mm < CHUNK) ? ysq[mbase + mm] : 0.f;
    }
    float a[4][4] = {};
    for (int dc = 0; dc < 8; ++dc) {
      const int d0 = dc * 32;
#pragma unroll
      for (int p = 0; p < 4; ++p) {
        int i = t + 256 * p;
        int m = i >> 3, dq = i & 7;
        int mm = m0 + m;
        int mg = mbase + ((mm < CHUNK) ? mm : 0);
        float4 v = *(const float4*)(Hm + (size_t)mg * DIM + d0 + 4 * dq);
        U[(4 * dq + 0) * 132 + m] = v.x; U[(4 * dq + 1) * 132 + m] = v.y;
        U[(4 * dq + 2) * 132 + m] = v.z; U[(4 * dq + 3) * 132 + m] = v.w;
      }
      __syncthreads();
#pragma unroll
      for (int dd = 0; dd < 32; ++dd) {
        const float4 qv = *(const float4*)(&Qt[(d0 + dd) * QT + 4 * qi]);
        const float4 mv = *(const float4*)(&U[dd * 132 + 4 * mi]);
        a[0][0] += qv.x * mv.x; a[0][1] += qv.x * mv.y; a[0][2] += qv.x * mv.z; a[0][3] += qv.x * mv.w;
        a[1][0] += qv.y * mv.x; a[1][1] += qv.y * mv.y; a[1][2] += qv.y * mv.z; a[1][3] += qv.y * mv.w;
        a[2][0] += qv.z * mv.x; a[2][1] += qv.z * mv.y; a[2][2] += qv.z * mv.z; a[2][3] += qv.z * mv.w;
        a[3][0] += qv.w * mv.x; a[3][1] += qv.w * mv.y; a[3][2] += qv.w * mv.z; a[3][3] += qv.w * mv.w;
      }
      __syncthreads();
    }
    // dots -> Sc region of U (Mt is dead until next mtile's staging)
#pragma unroll
    for (int aa = 0; aa < 4; ++aa)
#pragma unroll
      for (int bb = 0; bb < 4; ++bb)
        U[(4 * qi + aa) * 129 + 4 * mi + bb] = a[aa][bb];
    __syncthreads();
    if (t < QT) {
      const float xq = xsh[t];
      const float omx = 1.f - xq;
      const int mlim = (CHUNK - m0 < MT) ? (CHUNK - m0) : MT;
      for (int m = 0; m < mlim; ++m) {
        const float dot = U[t * 129 + m];
        const float yq = ysh[m];
        float diff = xq + yq - 2.f * dot; if (diff < 0.f) diff = 0.f;
        const float den = omx * (1.f - yq) + 1e-8f;
        const float tt = diff / den;
        if (tt < curMax) {
          const int gid = mbase + m0 + m;
#pragma unroll
          for (int j = 0; j < T16; ++j) if (j == curArg) { topS[j] = tt; topI[j] = gid; }
          curMax = -1.f;
#pragma unroll
          for (int j = 0; j < T16; ++j) if (topS[j] > curMax) { curMax = topS[j]; curArg = j; }
        }
      }
    }
  }
  if (t < QT) {
    const int base = ((q0 + t) * NCHUNK + blockIdx.y) * T16;
#pragma unroll
    for (int j = 0; j < T16; ++j) { cand_s[base + j] = topS[j]; cand_i[base + j] = topI[j]; }
  }
}

// ---------------------------------------------------------------------------
// Finalize: per query (1 wave): merge 400 candidates -> top-16 (fp32 score,
// idx tie-break), fp64 rescore -> exact top-8 order, softmax, mask gather.
// ---------------------------------------------------------------------------
__global__ __launch_bounds__(64) void finalize_kernel(
    const float* __restrict__ Hq, const float* __restrict__ Hm,
    const float* __restrict__ masks,
    const float* __restrict__ cand_s, const int* __restrict__ cand_i,
    float* __restrict__ outW, float* __restrict__ outH)
{
  const int q = blockIdx.x;
  const int lane = threadIdx.x;
  const int NC = NCHUNK * T16;  // 400

  unsigned long long pk[7];
  const float* cs = cand_s + (size_t)q * NC;
  const int*   ci = cand_i + (size_t)q * NC;
#pragma unroll
  for (int s = 0; s < 7; ++s) {
    int c = lane + 64 * s;
    if (c < NC)
      pk[s] = (((unsigned long long)__float_as_uint(cs[c])) << 32) | (unsigned int)ci[c];
    else
      pk[s] = ~0ULL;
  }

  __shared__ int    selIdx[T16];
  __shared__ double dArr[T16];
  __shared__ int    fin_i[KSEL];
  __shared__ double fin_d[KSEL];
  __shared__ double ew[KSEL];

  for (int r = 0; r < T16; ++r) {
    unsigned long long lm = ~0ULL;
#pragma unroll
    for (int s = 0; s < 7; ++s) lm = (pk[s] < lm) ? pk[s] : lm;
    unsigned long long gm = lm;
#pragma unroll
    for (int off = 1; off < 64; off <<= 1) {
      unsigned long long o = __shfl_xor(gm, off);
      gm = (o < gm) ? o : gm;
    }
    bool done = false;
#pragma unroll
    for (int s = 0; s < 7; ++s) if (!done && pk[s] == gm) { pk[s] = ~0ULL; done = true; }
    if (lane == 0) selIdx[r] = (int)(unsigned int)(gm & 0xffffffffULL);
  }
  __syncthreads();

  const float4 q4 = *(const float4*)(Hq + (size_t)q * DIM + 4 * lane);
  double xp_ = (double)q4.x * q4.x + (double)q4.y * q4.y + (double)q4.z * q4.z + (double)q4.w * q4.w;
#pragma unroll
  for (int off = 1; off < 64; off <<= 1) xp_ += __shfl_xor(xp_, off);
  const double xsq = xp_;

  for (int r = 0; r < T16; ++r) {
    const int cidx = selIdx[r];
    const float4 m4 = *(const float4*)(Hm + (size_t)cidx * DIM + 4 * lane);
    double dp = (double)q4.x * m4.x + (double)q4.y * m4.y + (double)q4.z * m4.z + (double)q4.w * m4.w;
    double yp = (double)m4.x * m4.x + (double)m4.y * m4.y + (double)m4.z * m4.z + (double)m4.w * m4.w;
#pragma unroll
    for (int off = 1; off < 64; off <<= 1) { dp += __shfl_xor(dp, off); yp += __shfl_xor(yp, off); }
    if (lane == 0) {
      double diff = xsq + yp - 2.0 * dp; if (diff < 0.0) diff = 0.0;
      double den = (1.0 - xsq) * (1.0 - yp);
      double arg = 1.0 + 2.0 * diff / (den + 1e-8);
      const double lo = 1.0 + 1e-6;
      if (arg < lo) arg = lo;
      dArr[r] = log(arg + sqrt(arg * arg - 1.0));   // arccosh
    }
  }
  __syncthreads();

  if (lane < T16) {
    const double dj = dArr[lane]; const int ij = selIdx[lane];
    int rank = 0;
#pragma unroll
    for (int i = 0; i < T16; ++i)
      rank += (dArr[i] < dj || (dArr[i] == dj && selIdx[i] < ij)) ? 1 : 0;
    if (rank < KSEL) { fin_d[rank] = dj; fin_i[rank] = ij; }
  }
  __syncthreads();
  if (lane < KSEL) ew[lane] = exp(fin_d[0] - fin_d[lane]);
  __syncthreads();
  if (lane < KSEL) {
    double ssum = 0.0;
#pragma unroll
    for (int i = 0; i < KSEL; ++i) ssum += ew[i];
    outW[(size_t)q * KSEL + lane] = (float)(ew[lane] / ssum);
  }
#pragma unroll
  for (int j = 0; j < KSEL; ++j) {
    const int row = fin_i[j];
    for (int l = lane; l < ATOMS; l += 64)
      outH[((size_t)q * KSEL + j) * ATOMS + l] = masks[(size_t)row * ATOMS + l];
  }
}

// ---------------------------------------------------------------------------
extern "C" void kernel_launch(void* const* d_in, const int* in_sizes, int n_in,
                              void* d_out, int out_size, void* d_ws, size_t ws_size,
                              hipStream_t stream) {
  const float* Q     = (const float*)d_in[0];   // [1024,256]
  const float* M     = (const float*)d_in[1];   // [50000,256]
  const float* masks = (const float*)d_in[2];   // [50000,200]
  const float* W     = (const float*)d_in[3];   // [256,256]
  const float* bv    = (const float*)d_in[4];   // [256]
  // d_in[5] = k (always 8, hard-coded)

  float* Hq  = (float*)d_ws;                         //   1,048,576 B
  float* Hm  = Hq + (size_t)B_Q * DIM;               //  51,200,000 B
  float* xsq = Hm + (size_t)N_M * DIM;               //       4,096 B
  float* ysq = xsq + B_Q;                            //     200,000 B
  float* cs  = ysq + N_M;                            //   1,638,400 B
  int*   cix = (int*)(cs + (size_t)B_Q * NCHUNK * T16); // 1,638,400 B  (~55.7 MB total)

  transform_kernel<<<B_Q / 32, 256, 0, stream>>>(Q, B_Q, W, bv, Hq, xsq);
  transform_kernel<<<(N_M + 31) / 32, 256, 0, stream>>>(M, N_M, W, bv, Hm, ysq);
  score_kernel<<<dim3(B_Q / QT, NCHUNK), 256, 0, stream>>>(Hq, Hm, xsq, ysq, cs, cix);
  finalize_kernel<<<B_Q, 64, 0, stream>>>(Hq, Hm, masks, cs, cix,
                                          (float*)d_out, (float*)d_out + (size_t)B_Q * KSEL);
}

// Round 2
// 846.668 us; speedup vs baseline: 2.6764x; 2.6764x over previous
//
#include <hip/hip_runtime.h>
#include <hip/hip_bf16.h>
#include <math.h>
#include <float.h>

#define B_Q   1024
#define N_M   50000
#define N_M_PAD 50048
#define DIM   256
#define ATOMS 200
#define KSEL  8
#define NCHUNK 40
#define CHUNK  1250       // N_M / NCHUNK exactly
#define MT    128
#define NMT   10          // ceil(CHUNK/MT)
#define T16   16          // candidates kept per (query, chunk)
#define NC    (NCHUNK * T16)   // 640 candidates per query

typedef __attribute__((ext_vector_type(8))) short bf16x8;
typedef __attribute__((ext_vector_type(4))) float f32x4;

static __device__ inline unsigned short f2bf(float f) {
  __hip_bfloat16 h = __float2bfloat16(f);   // RNE
  return *reinterpret_cast<unsigned short*>(&h);
}

// ---------------------------------------------------------------------------
// Transform: H = to_poincare(X @ W + b), fp64 accumulation for fidelity.
// Emits fp32 H (finalize rescore), bf16 H (MFMA scoring), aux = {ssq, 1/(1-ssq)}.
// Block = 256 threads = 4 waves; each wave owns 8 rows; lane owns 4 columns.
// ---------------------------------------------------------------------------
__global__ __launch_bounds__(256) void transform_kernel(
    const float* __restrict__ X, int nrows,
    const float* __restrict__ W, const float* __restrict__ bvec,
    float* __restrict__ H, unsigned short* __restrict__ Hb,
    float2* __restrict__ aux)
{
  const int t  = threadIdx.x;
  const int tx = t & 63;
  const int ty = t >> 6;
  const int row0 = blockIdx.x * 32 + ty * 8;

  const float* xp[8];
#pragma unroll
  for (int r = 0; r < 8; ++r) {
    int row = row0 + r;
    if (row >= nrows) row = nrows - 1;   // clamp; stores guarded below
    xp[r] = X + (size_t)row * DIM;
  }

  double acc[8][4];
#pragma unroll
  for (int r = 0; r < 8; ++r)
#pragma unroll
    for (int j = 0; j < 4; ++j) acc[r][j] = 0.0;

  for (int d = 0; d < DIM; d += 4) {
    float w[4][4];
#pragma unroll
    for (int dd = 0; dd < 4; ++dd) {
      const float* wr = W + (size_t)(d + dd) * DIM + tx;
      w[dd][0] = wr[0]; w[dd][1] = wr[64]; w[dd][2] = wr[128]; w[dd][3] = wr[192];
    }
#pragma unroll
    for (int r = 0; r < 8; ++r) {
      const float4 x4 = *(const float4*)(xp[r] + d);
#pragma unroll
      for (int j = 0; j < 4; ++j) {
        acc[r][j] += (double)x4.x * (double)w[0][j];
        acc[r][j] += (double)x4.y * (double)w[1][j];
        acc[r][j] += (double)x4.z * (double)w[2][j];
        acc[r][j] += (double)x4.w * (double)w[3][j];
      }
    }
  }

  float bv[4];
  bv[0] = bvec[tx]; bv[1] = bvec[tx + 64]; bv[2] = bvec[tx + 128]; bv[3] = bvec[tx + 192];

#pragma unroll
  for (int r = 0; r < 8; ++r) {
    const int row = row0 + r;
    if (row < nrows) {                   // wave-uniform branch (row uniform per wave)
      double h[4], nsq = 0.0;
#pragma unroll
      for (int j = 0; j < 4; ++j) { h[j] = tanh(acc[r][j] + (double)bv[j]); nsq += h[j] * h[j]; }
#pragma unroll
      for (int off = 1; off < 64; off <<= 1) nsq += __shfl_xor(nsq, off);
      const double nrm = sqrt(nsq);
      const double scl = (nrm > 0.95) ? (0.95 / nrm) : 1.0;
      float u[4]; double ysq = 0.0;
#pragma unroll
      for (int j = 0; j < 4; ++j) { u[j] = (float)(h[j] * scl); ysq += (double)u[j] * (double)u[j]; }
#pragma unroll
      for (int off = 1; off < 64; off <<= 1) ysq += __shfl_xor(ysq, off);
      float* Hr = H + (size_t)row * DIM;
      Hr[tx] = u[0]; Hr[tx + 64] = u[1]; Hr[tx + 128] = u[2]; Hr[tx + 192] = u[3];
      unsigned short* Hbr = Hb + (size_t)row * DIM;
      Hbr[tx]       = f2bf(u[0]); Hbr[tx + 64]  = f2bf(u[1]);
      Hbr[tx + 128] = f2bf(u[2]); Hbr[tx + 192] = f2bf(u[3]);
      if (tx == 0) aux[row] = make_float2((float)ysq, (float)(1.0 / (1.0 - ysq)));
    }
  }
}

// ---------------------------------------------------------------------------
// Score (MFMA): block = 32 queries x 1 chunk (1250 memories). 4 waves; wave w
// owns memory cols [mt*128 + w*32, +32). A-fragments (32q x K=256, bf16) live
// in 64 VGPRs for the whole kernel; B-fragments stream global->VGPR (16B/lane,
// L1-coalesced). Selection score s = max(xsq+ysq-2*dot,0) * 1/(1-ysq) is
// per-query monotone with the hyperbolic distance. Scores round-trip a 16.5KB
// LDS tile; 256-thread scan (8 threads/query) keeps per-thread top-8; 8-lane
// shuffle butterfly merges to per-(query,chunk) top-16 candidates.
// MFMA layouts (gfx950, 16x16x32 bf16): A[m=lane&15][k=(lane>>4)*8+j],
// C/D col=lane&15 row=(lane>>4)*4+reg (HW-verified); B assumed mirror of A.
// ---------------------------------------------------------------------------
__global__ __launch_bounds__(256) void score_kernel(
    const unsigned short* __restrict__ Hqb, const unsigned short* __restrict__ Hmb,
    const float2* __restrict__ auxq, const float2* __restrict__ auxm,
    float* __restrict__ cand_s, int* __restrict__ cand_i)
{
  __shared__ float Sc[32 * 129];
  const int t    = threadIdx.x;
  const int lane = t & 63;
  const int wave = t >> 6;
  const int q0   = blockIdx.x * 32;
  const int c    = blockIdx.y;
  const int mbase = c * CHUNK;

  const int lx   = lane & 15;
  const int quad = lane >> 4;

  // A fragments: [kstep][q-subtile]
  bf16x8 Af[8][2];
#pragma unroll
  for (int ks = 0; ks < 8; ++ks)
#pragma unroll
    for (int qs = 0; qs < 2; ++qs) {
      const size_t row = (size_t)(q0 + qs * 16 + lx);
      Af[ks][qs] = *(const bf16x8*)(Hqb + row * DIM + ks * 32 + quad * 8);
    }
  float xq[2][4];
#pragma unroll
  for (int qs = 0; qs < 2; ++qs)
#pragma unroll
    for (int r = 0; r < 4; ++r)
      xq[qs][r] = auxq[q0 + qs * 16 + quad * 4 + r].x;

  // scan-phase identity: 8 threads per query, contiguous lanes per query
  const int sq = t >> 3;
  const int sp = t & 7;

  float topS[KSEL]; int topI[KSEL];
  float curMax = FLT_MAX; int curArg = 0;
#pragma unroll
  for (int j = 0; j < KSEL; ++j) { topS[j] = FLT_MAX; topI[j] = 0; }

  for (int mt = 0; mt < NMT; ++mt) {
    const int mrow0 = mbase + mt * MT + wave * 32;
    const float2 aux0 = auxm[mrow0 + lx];
    const float2 aux1 = auxm[mrow0 + 16 + lx];
    f32x4 acc[2][2];
#pragma unroll
    for (int qs = 0; qs < 2; ++qs)
#pragma unroll
      for (int ms = 0; ms < 2; ++ms) { acc[qs][ms][0] = 0.f; acc[qs][ms][1] = 0.f; acc[qs][ms][2] = 0.f; acc[qs][ms][3] = 0.f; }
#pragma unroll
    for (int ks = 0; ks < 8; ++ks) {
      const bf16x8 b0 = *(const bf16x8*)(Hmb + (size_t)(mrow0 + lx)      * DIM + ks * 32 + quad * 8);
      const bf16x8 b1 = *(const bf16x8*)(Hmb + (size_t)(mrow0 + 16 + lx) * DIM + ks * 32 + quad * 8);
      acc[0][0] = __builtin_amdgcn_mfma_f32_16x16x32_bf16(Af[ks][0], b0, acc[0][0], 0, 0, 0);
      acc[0][1] = __builtin_amdgcn_mfma_f32_16x16x32_bf16(Af[ks][0], b1, acc[0][1], 0, 0, 0);
      acc[1][0] = __builtin_amdgcn_mfma_f32_16x16x32_bf16(Af[ks][1], b0, acc[1][0], 0, 0, 0);
      acc[1][1] = __builtin_amdgcn_mfma_f32_16x16x32_bf16(Af[ks][1], b1, acc[1][1], 0, 0, 0);
    }
    __syncthreads();           // previous mtile's scan finished reading Sc
#pragma unroll
    for (int qs = 0; qs < 2; ++qs)
#pragma unroll
      for (int ms = 0; ms < 2; ++ms) {
        const float ym = ms ? aux1.x : aux0.x;
        const float ro = ms ? aux1.y : aux0.y;
        const int mcol = wave * 32 + ms * 16 + lx;
#pragma unroll
        for (int r = 0; r < 4; ++r) {
          const float s = fmaxf(fmaf(-2.f, acc[qs][ms][r], xq[qs][r] + ym), 0.f) * ro;
          Sc[(qs * 16 + quad * 4 + r) * 129 + mcol] = s;
        }
      }
    __syncthreads();
    const int rem  = CHUNK - mt * MT;
    const int mlim = (rem < MT) ? rem : MT;
    const int gbase = mbase + mt * MT;
#pragma unroll
    for (int i = 0; i < 16; ++i) {
      const int m = sp * 16 + i;
      if (m < mlim) {
        const float s = Sc[sq * 129 + m];
        if (s < curMax) {
          const int gid = gbase + m;
#pragma unroll
          for (int j = 0; j < KSEL; ++j) if (j == curArg) { topS[j] = s; topI[j] = gid; }
          curMax = -1.f;
#pragma unroll
          for (int j = 0; j < KSEL; ++j) if (topS[j] > curMax) { curMax = topS[j]; curArg = j; }
        }
      }
    }
  }

  // merge 8 partial top-8s per query -> top-16 -> cand (8-lane butterfly)
  unsigned long long pk[KSEL];
#pragma unroll
  for (int j = 0; j < KSEL; ++j)
    pk[j] = (((unsigned long long)__float_as_uint(topS[j])) << 32) | (unsigned int)topI[j];

  const size_t cbase = ((size_t)(q0 + sq) * NCHUNK + c) * T16;
  for (int r = 0; r < T16; ++r) {
    unsigned long long lm = ~0ULL;
#pragma unroll
    for (int j = 0; j < KSEL; ++j) lm = (pk[j] < lm) ? pk[j] : lm;
    unsigned long long gm = lm;
#pragma unroll
    for (int off = 1; off < 8; off <<= 1) {
      unsigned long long o = __shfl_xor(gm, off);
      gm = (o < gm) ? o : gm;
    }
    bool done = false;
#pragma unroll
    for (int j = 0; j < KSEL; ++j) if (!done && pk[j] == gm) { pk[j] = ~0ULL; done = true; }
    if (sp == 0) {
      cand_s[cbase + r] = __uint_as_float((unsigned int)(gm >> 32));
      cand_i[cbase + r] = (int)(unsigned int)(gm & 0xffffffffu);
    }
  }
}

// ---------------------------------------------------------------------------
// Finalize: per query (1 wave): merge 640 candidates -> top-16 (fp32 score,
// idx tie-break), fp64 rescore -> exact top-8 order, softmax, mask gather.
// ---------------------------------------------------------------------------
__global__ __launch_bounds__(64) void finalize_kernel(
    const float* __restrict__ Hq, const float* __restrict__ Hm,
    const float* __restrict__ masks,
    const float* __restrict__ cand_s, const int* __restrict__ cand_i,
    float* __restrict__ outW, float* __restrict__ outH)
{
  const int q = blockIdx.x;
  const int lane = threadIdx.x;

  unsigned long long pk[NC / 64];   // 10
  const float* cs = cand_s + (size_t)q * NC;
  const int*   ci = cand_i + (size_t)q * NC;
#pragma unroll
  for (int s = 0; s < NC / 64; ++s) {
    int c = lane + 64 * s;
    pk[s] = (((unsigned long long)__float_as_uint(cs[c])) << 32) | (unsigned int)ci[c];
  }

  __shared__ int    selIdx[T16];
  __shared__ double dArr[T16];
  __shared__ int    fin_i[KSEL];
  __shared__ double fin_d[KSEL];
  __shared__ double ew[KSEL];

  for (int r = 0; r < T16; ++r) {
    unsigned long long lm = ~0ULL;
#pragma unroll
    for (int s = 0; s < NC / 64; ++s) lm = (pk[s] < lm) ? pk[s] : lm;
    unsigned long long gm = lm;
#pragma unroll
    for (int off = 1; off < 64; off <<= 1) {
      unsigned long long o = __shfl_xor(gm, off);
      gm = (o < gm) ? o : gm;
    }
    bool done = false;
#pragma unroll
    for (int s = 0; s < NC / 64; ++s) if (!done && pk[s] == gm) { pk[s] = ~0ULL; done = true; }
    if (lane == 0) selIdx[r] = (int)(unsigned int)(gm & 0xffffffffULL);
  }
  __syncthreads();

  const float4 q4 = *(const float4*)(Hq + (size_t)q * DIM + 4 * lane);
  double xp_ = (double)q4.x * q4.x + (double)q4.y * q4.y + (double)q4.z * q4.z + (double)q4.w * q4.w;
#pragma unroll
  for (int off = 1; off < 64; off <<= 1) xp_ += __shfl_xor(xp_, off);
  const double xsq = xp_;

  for (int r = 0; r < T16; ++r) {
    const int cidx = selIdx[r];
    const float4 m4 = *(const float4*)(Hm + (size_t)cidx * DIM + 4 * lane);
    double dp = (double)q4.x * m4.x + (double)q4.y * m4.y + (double)q4.z * m4.z + (double)q4.w * m4.w;
    double yp = (double)m4.x * m4.x + (double)m4.y * m4.y + (double)m4.z * m4.z + (double)m4.w * m4.w;
#pragma unroll
    for (int off = 1; off < 64; off <<= 1) { dp += __shfl_xor(dp, off); yp += __shfl_xor(yp, off); }
    if (lane == 0) {
      double diff = xsq + yp - 2.0 * dp; if (diff < 0.0) diff = 0.0;
      double den = (1.0 - xsq) * (1.0 - yp);
      double arg = 1.0 + 2.0 * diff / (den + 1e-8);
      const double lo = 1.0 + 1e-6;
      if (arg < lo) arg = lo;
      dArr[r] = log(arg + sqrt(arg * arg - 1.0));   // arccosh
    }
  }
  __syncthreads();

  if (lane < T16) {
    const double dj = dArr[lane]; const int ij = selIdx[lane];
    int rank = 0;
#pragma unroll
    for (int i = 0; i < T16; ++i)
      rank += (dArr[i] < dj || (dArr[i] == dj && selIdx[i] < ij)) ? 1 : 0;
    if (rank < KSEL) { fin_d[rank] = dj; fin_i[rank] = ij; }
  }
  __syncthreads();
  if (lane < KSEL) ew[lane] = exp(fin_d[0] - fin_d[lane]);
  __syncthreads();
  if (lane < KSEL) {
    double ssum = 0.0;
#pragma unroll
    for (int i = 0; i < KSEL; ++i) ssum += ew[i];
    outW[(size_t)q * KSEL + lane] = (float)(ew[lane] / ssum);
  }
#pragma unroll
  for (int j = 0; j < KSEL; ++j) {
    const int row = fin_i[j];
    for (int l = lane; l < ATOMS; l += 64)
      outH[((size_t)q * KSEL + j) * ATOMS + l] = masks[(size_t)row * ATOMS + l];
  }
}

// ---------------------------------------------------------------------------
extern "C" void kernel_launch(void* const* d_in, const int* in_sizes, int n_in,
                              void* d_out, int out_size, void* d_ws, size_t ws_size,
                              hipStream_t stream) {
  const float* Q     = (const float*)d_in[0];   // [1024,256]
  const float* M     = (const float*)d_in[1];   // [50000,256]
  const float* masks = (const float*)d_in[2];   // [50000,200]
  const float* W     = (const float*)d_in[3];   // [256,256]
  const float* bv    = (const float*)d_in[4];   // [256]
  // d_in[5] = k (always 8, hard-coded)

  char* w = (char*)d_ws;
  float*          Hq   = (float*)(w);                       //  1,048,576 B
  float*          Hm   = (float*)(w + 1048576);             // 51,200,000 B
  unsigned short* Hqb  = (unsigned short*)(w + 52248576);   //    524,288 B
  unsigned short* Hmb  = (unsigned short*)(w + 52772864);   // 25,624,576 B (padded to 50048 rows)
  float2*         auxq = (float2*)(w + 78397440);           //      8,192 B
  float2*         auxm = (float2*)(w + 78405632);           //    400,384 B (padded)
  float*          cs   = (float*)(w + 78806016);            //  2,621,440 B
  int*            cix  = (int*)(w + 81427456);              //  2,621,440 B -> 84,048,896 total

  transform_kernel<<<B_Q / 32, 256, 0, stream>>>(Q, B_Q, W, bv, Hq, Hqb, auxq);
  transform_kernel<<<(N_M + 31) / 32, 256, 0, stream>>>(M, N_M, W, bv, Hm, Hmb, auxm);
  score_kernel<<<dim3(B_Q / 32, NCHUNK), 256, 0, stream>>>(Hqb, Hmb, auxq, auxm, cs, cix);
  finalize_kernel<<<B_Q, 64, 0, stream>>>(Hq, Hm, masks, cs, cix,
                                          (float*)d_out, (float*)d_out + (size_t)B_Q * KSEL);
}

// Round 4
// 492.894 us; speedup vs baseline: 4.5974x; 1.7177x over previous
//
#include <hip/hip_runtime.h>
#include <hip/hip_bf16.h>
#include <math.h>
#include <float.h>

#define B_Q   1024
#define N_M   50000
#define DIM   256
#define ATOMS 200
#define KSEL  8
#define NCHUNK 40
#define CHUNK  1250       // N_M / NCHUNK exactly
#define MT    128
#define NMT   10          // CHUNK/MT rounded up
#define T16   16          // candidates kept per (query, chunk)
#define NC    (NCHUNK * T16)   // 640 candidates per query
#define AP    264         // A-plane LDS row stride in bf16 elems (528B, 16B-aligned)

typedef __attribute__((ext_vector_type(8))) short bf16x8;
typedef __attribute__((ext_vector_type(4))) float f32x4;

static __device__ inline unsigned short f2bf(float f) {
  __hip_bfloat16 h = __float2bfloat16(f);   // RNE
  return *reinterpret_cast<unsigned short*>(&h);
}

// 3-way bf16 Dekker split: x ~= s1+s2+s3, residual <= 2^-27 |x|
static __device__ inline void split3(float x, unsigned short& s1,
                                     unsigned short& s2, unsigned short& s3) {
  __hip_bfloat16 b1 = __float2bfloat16(x);
  float f1 = __bfloat162float(b1);
  float r1 = x - f1;
  __hip_bfloat16 b2 = __float2bfloat16(r1);
  float f2 = __bfloat162float(b2);
  __hip_bfloat16 b3 = __float2bfloat16(r1 - f2);
  s1 = *reinterpret_cast<unsigned short*>(&b1);
  s2 = *reinterpret_cast<unsigned short*>(&b2);
  s3 = *reinterpret_cast<unsigned short*>(&b3);
}

// fast fp64 tanh via exp2 poly: rel err ~1e-15, plenty for fp32-stored H.
static __device__ inline double fast_tanh(double x) {
  double ax = fabs(x);
  double z = ax * 2.8853900817779268147;          // 2*log2(e)
  z = fmin(z, 120.0);                              // safety clamp
  double n = rint(z);
  double f = z - n;                                // [-0.5, 0.5]
  double p = 2.5678435993488202e-11;
  p = fma(p, f, 4.4457542277961220e-10);
  p = fma(p, f, 7.0549116208011225e-09);
  p = fma(p, f, 1.0178086009239699e-07);
  p = fma(p, f, 1.3215486790144305e-06);
  p = fma(p, f, 1.5252733804059838e-05);
  p = fma(p, f, 1.5403530393381608e-04);
  p = fma(p, f, 1.3333558146428443e-03);
  p = fma(p, f, 9.6181291076284772e-03);
  p = fma(p, f, 5.5504108664821580e-02);
  p = fma(p, f, 2.4022650695910071e-01);
  p = fma(p, f, 6.9314718055994531e-01);
  p = fma(p, f, 1.0);
  long long ni = (long long)n;                     // >= 0
  double twon = __longlong_as_double((ni + 1023LL) << 52);
  double E = p * twon;                             // exp(2*ax)
  double tt = 1.0 - 2.0 / (E + 1.0);
  tt = (ax > 19.0) ? 1.0 : tt;
  return (x >= 0.0) ? tt : -tt;
}

// ---------------------------------------------------------------------------
// W pre-split: Wt planes [n][k] (transposed) as bf16 triple. 256x256, tiny.
// ---------------------------------------------------------------------------
__global__ __launch_bounds__(256) void wsplit_kernel(
    const float* __restrict__ W,
    unsigned short* __restrict__ Wt1, unsigned short* __restrict__ Wt2,
    unsigned short* __restrict__ Wt3)
{
  const int n = blockIdx.x;
  const int k = threadIdx.x;
  unsigned short s1, s2, s3;
  split3(W[(size_t)k * DIM + n], s1, s2, s3);
  Wt1[(size_t)n * DIM + k] = s1;
  Wt2[(size_t)n * DIM + k] = s2;
  Wt3[(size_t)n * DIM + k] = s3;
}

// ---------------------------------------------------------------------------
// Transform: H = to_poincare(X @ W + b); X@W via bf16 MFMA with 3-way Dekker
// split (6 product orders). Dominant x1*w1 term: C=0 per K=32 MFMA, drained
// to fp64 each k-step -> z error ~1.5e-7, H error ~ fp32-storage level.
// Layouts are the HW-verified 16x16x32_bf16 conventions from score_kernel:
// A[m=lane&15][k=quad*8+j] (LDS planes), B[n=lane&15][k=quad*8+j] (Wt rows),
// D col=lane&15, row=quad*4+reg.
// Block = 16 rows x 256 cols; wave w owns col-tiles n0 = 64w + 16c, c=0..3.
// nrows must be a multiple of 16 (1024, 50000 both are).
// ---------------------------------------------------------------------------
__global__ __launch_bounds__(256) void transform_kernel(
    const float* __restrict__ X, int nrows,
    const unsigned short* __restrict__ Wt1, const unsigned short* __restrict__ Wt2,
    const unsigned short* __restrict__ Wt3, const float* __restrict__ bvec,
    float* __restrict__ H, unsigned short* __restrict__ Hb,
    float2* __restrict__ aux)
{
  __shared__ __align__(16) unsigned short X1s[16 * AP];
  __shared__ __align__(16) unsigned short X2s[16 * AP];
  __shared__ __align__(16) unsigned short X3s[16 * AP];
  __shared__ double red[4][16];

  const int t    = threadIdx.x;
  const int lane = t & 63;
  const int wave = t >> 6;
  const int row0 = blockIdx.x * 16;

  // stage + split X tile [16][256]
  {
    const int r  = t >> 4;
    const int c0 = (t & 15) * 16;
    const float* src = X + (size_t)(row0 + r) * DIM + c0;
#pragma unroll
    for (int i = 0; i < 16; ++i) {
      unsigned short s1, s2, s3;
      split3(src[i], s1, s2, s3);
      X1s[r * AP + c0 + i] = s1;
      X2s[r * AP + c0 + i] = s2;
      X3s[r * AP + c0 + i] = s3;
    }
  }
  __syncthreads();

  const int lx   = lane & 15;    // A row m / B col n / D col
  const int quad = lane >> 4;    // k-group / D row-quad

  double d[4][4];
  f32x4 cacc[4];
#pragma unroll
  for (int c = 0; c < 4; ++c) {
#pragma unroll
    for (int r = 0; r < 4; ++r) d[c][r] = 0.0;
    cacc[c][0] = 0.f; cacc[c][1] = 0.f; cacc[c][2] = 0.f; cacc[c][3] = 0.f;
  }
  const f32x4 zero4 = {0.f, 0.f, 0.f, 0.f};

#pragma unroll
  for (int ks = 0; ks < 8; ++ks) {
    const int ko = ks * 32 + quad * 8;
    const bf16x8 a1 = *(const bf16x8*)(X1s + lx * AP + ko);
    const bf16x8 a2 = *(const bf16x8*)(X2s + lx * AP + ko);
    const bf16x8 a3 = *(const bf16x8*)(X3s + lx * AP + ko);
#pragma unroll
    for (int c = 0; c < 4; ++c) {
      const size_t nrow = (size_t)(wave * 64 + c * 16 + lx) * DIM + ko;
      const bf16x8 b1 = *(const bf16x8*)(Wt1 + nrow);
      const bf16x8 b2 = *(const bf16x8*)(Wt2 + nrow);
      const bf16x8 b3 = *(const bf16x8*)(Wt3 + nrow);
      const f32x4 mm = __builtin_amdgcn_mfma_f32_16x16x32_bf16(a1, b1, zero4, 0, 0, 0);
      cacc[c] = __builtin_amdgcn_mfma_f32_16x16x32_bf16(a1, b2, cacc[c], 0, 0, 0);
      cacc[c] = __builtin_amdgcn_mfma_f32_16x16x32_bf16(a2, b1, cacc[c], 0, 0, 0);
      cacc[c] = __builtin_amdgcn_mfma_f32_16x16x32_bf16(a1, b3, cacc[c], 0, 0, 0);
      cacc[c] = __builtin_amdgcn_mfma_f32_16x16x32_bf16(a2, b2, cacc[c], 0, 0, 0);
      cacc[c] = __builtin_amdgcn_mfma_f32_16x16x32_bf16(a3, b1, cacc[c], 0, 0, 0);
      d[c][0] += (double)mm[0]; d[c][1] += (double)mm[1];
      d[c][2] += (double)mm[2]; d[c][3] += (double)mm[3];
    }
  }

  // bias + tanh: lane holds rows 4*quad+r, col wave*64 + 16c + lx
  double h[4][4];
#pragma unroll
  for (int c = 0; c < 4; ++c) {
    const double bb = (double)bvec[wave * 64 + 16 * c + lx];
#pragma unroll
    for (int r = 0; r < 4; ++r)
      h[c][r] = fast_tanh(d[c][r] + (double)cacc[c][r] + bb);
  }

  // row-norm: partial over this wave's 64 cols, rows 4*quad+r
  double p[4];
#pragma unroll
  for (int r = 0; r < 4; ++r)
    p[r] = h[0][r] * h[0][r] + h[1][r] * h[1][r] + h[2][r] * h[2][r] + h[3][r] * h[3][r];
#pragma unroll
  for (int off = 1; off < 16; off <<= 1)
#pragma unroll
    for (int r = 0; r < 4; ++r) p[r] += __shfl_xor(p[r], off);
  if (lx == 0)
#pragma unroll
    for (int r = 0; r < 4; ++r) red[wave][4 * quad + r] = p[r];
  __syncthreads();

  double s[4];
#pragma unroll
  for (int r = 0; r < 4; ++r) {
    const int row = 4 * quad + r;
    const double nsq = red[0][row] + red[1][row] + red[2][row] + red[3][row];
    const double nrm = sqrt(nsq);
    s[r] = (nrm > 0.95) ? (0.95 / nrm) : 1.0;
  }
  __syncthreads();   // everyone done reading red before reuse

  float u[4][4];
  double py[4] = {0.0, 0.0, 0.0, 0.0};
#pragma unroll
  for (int c = 0; c < 4; ++c)
#pragma unroll
    for (int r = 0; r < 4; ++r) {
      u[c][r] = (float)(h[c][r] * s[r]);
      py[r] += (double)u[c][r] * (double)u[c][r];
    }
#pragma unroll
  for (int off = 1; off < 16; off <<= 1)
#pragma unroll
    for (int r = 0; r < 4; ++r) py[r] += __shfl_xor(py[r], off);
  if (lx == 0)
#pragma unroll
    for (int r = 0; r < 4; ++r) red[wave][4 * quad + r] = py[r];

  // stores
#pragma unroll
  for (int c = 0; c < 4; ++c) {
    const int n = wave * 64 + 16 * c + lx;
#pragma unroll
    for (int r = 0; r < 4; ++r) {
      const size_t row = (size_t)(row0 + 4 * quad + r);
      H[row * DIM + n]  = u[c][r];
      Hb[row * DIM + n] = f2bf(u[c][r]);
    }
  }
  __syncthreads();
  if (t < 16) {
    const double ysq = red[0][t] + red[1][t] + red[2][t] + red[3][t];
    aux[row0 + t] = make_float2((float)ysq, (float)(1.0 / (1.0 - ysq)));
  }
}

// ---------------------------------------------------------------------------
// Score (MFMA): block = 32 queries x 1 chunk (1250 memories). Grid is
// (chunk, qtile) so linear block id = c + 40*q -> XCD (id%8) = c%8: all 32
// q-blocks of a chunk co-run on one XCD, its 640KB Hmb chunk stays in that
// XCD's L2. A-fragments (32q x K=256, bf16) in 64 VGPRs; B streams global.
// Selection score s = max(xsq+ysq-2*dot,0) * 1/(1-ysq): per-query monotone
// with the hyperbolic distance. Scores round-trip 16.5KB LDS; 256-thread
// scan keeps per-thread top-8; 8-lane butterfly merges to per-chunk top-16.
// ---------------------------------------------------------------------------
__global__ __launch_bounds__(256) void score_kernel(
    const unsigned short* __restrict__ Hqb, const unsigned short* __restrict__ Hmb,
    const float2* __restrict__ auxq, const float2* __restrict__ auxm,
    float* __restrict__ cand_s, int* __restrict__ cand_i)
{
  __shared__ float Sc[32 * 129];
  const int t    = threadIdx.x;
  const int lane = t & 63;
  const int wave = t >> 6;
  const int q0   = blockIdx.y * 32;
  const int c    = blockIdx.x;
  const int mbase = c * CHUNK;

  const int lx   = lane & 15;
  const int quad = lane >> 4;

  // A fragments: [kstep][q-subtile]
  bf16x8 Af[8][2];
#pragma unroll
  for (int ks = 0; ks < 8; ++ks)
#pragma unroll
    for (int qs = 0; qs < 2; ++qs) {
      const size_t row = (size_t)(q0 + qs * 16 + lx);
      Af[ks][qs] = *(const bf16x8*)(Hqb + row * DIM + ks * 32 + quad * 8);
    }
  float xq[2][4];
#pragma unroll
  for (int qs = 0; qs < 2; ++qs)
#pragma unroll
    for (int r = 0; r < 4; ++r)
      xq[qs][r] = auxq[q0 + qs * 16 + quad * 4 + r].x;

  // scan-phase identity: 8 threads per query
  const int sq = t >> 3;
  const int sp = t & 7;

  float topS[KSEL]; int topI[KSEL];
  float curMax = FLT_MAX; int curArg = 0;
#pragma unroll
  for (int j = 0; j < KSEL; ++j) { topS[j] = FLT_MAX; topI[j] = 0; }

  for (int mt = 0; mt < NMT; ++mt) {
    const int mrow0 = mbase + mt * MT + wave * 32;
    const float2 aux0 = auxm[mrow0 + lx];
    const float2 aux1 = auxm[mrow0 + 16 + lx];
    f32x4 acc[2][2];
#pragma unroll
    for (int qs = 0; qs < 2; ++qs)
#pragma unroll
      for (int ms = 0; ms < 2; ++ms) { acc[qs][ms][0] = 0.f; acc[qs][ms][1] = 0.f; acc[qs][ms][2] = 0.f; acc[qs][ms][3] = 0.f; }
#pragma unroll
    for (int ks = 0; ks < 8; ++ks) {
      const bf16x8 b0 = *(const bf16x8*)(Hmb + (size_t)(mrow0 + lx)      * DIM + ks * 32 + quad * 8);
      const bf16x8 b1 = *(const bf16x8*)(Hmb + (size_t)(mrow0 + 16 + lx) * DIM + ks * 32 + quad * 8);
      acc[0][0] = __builtin_amdgcn_mfma_f32_16x16x32_bf16(Af[ks][0], b0, acc[0][0], 0, 0, 0);
      acc[0][1] = __builtin_amdgcn_mfma_f32_16x16x32_bf16(Af[ks][0], b1, acc[0][1], 0, 0, 0);
      acc[1][0] = __builtin_amdgcn_mfma_f32_16x16x32_bf16(Af[ks][1], b0, acc[1][0], 0, 0, 0);
      acc[1][1] = __builtin_amdgcn_mfma_f32_16x16x32_bf16(Af[ks][1], b1, acc[1][1], 0, 0, 0);
    }
    __syncthreads();           // previous mtile's scan finished reading Sc
#pragma unroll
    for (int qs = 0; qs < 2; ++qs)
#pragma unroll
      for (int ms = 0; ms < 2; ++ms) {
        const float ym = ms ? aux1.x : aux0.x;
        const float ro = ms ? aux1.y : aux0.y;
        const int mcol = wave * 32 + ms * 16 + lx;
#pragma unroll
        for (int r = 0; r < 4; ++r) {
          const float s = fmaxf(fmaf(-2.f, acc[qs][ms][r], xq[qs][r] + ym), 0.f) * ro;
          Sc[(qs * 16 + quad * 4 + r) * 129 + mcol] = s;
        }
      }
    __syncthreads();
    const int rem  = CHUNK - mt * MT;
    const int mlim = (rem < MT) ? rem : MT;
    const int gbase = mbase + mt * MT;
#pragma unroll
    for (int i = 0; i < 16; ++i) {
      const int m = sp * 16 + i;
      if (m < mlim) {
        const float s = Sc[sq * 129 + m];
        if (s < curMax) {
          const int gid = gbase + m;
#pragma unroll
          for (int j = 0; j < KSEL; ++j) if (j == curArg) { topS[j] = s; topI[j] = gid; }
          curMax = -1.f;
#pragma unroll
          for (int j = 0; j < KSEL; ++j) if (topS[j] > curMax) { curMax = topS[j]; curArg = j; }
        }
      }
    }
  }

  // merge 8 partial top-8s per query -> top-16 -> cand (8-lane butterfly)
  unsigned long long pk[KSEL];
#pragma unroll
  for (int j = 0; j < KSEL; ++j)
    pk[j] = (((unsigned long long)__float_as_uint(topS[j])) << 32) | (unsigned int)topI[j];

  const size_t cbase = ((size_t)(q0 + sq) * NCHUNK + c) * T16;
  for (int r = 0; r < T16; ++r) {
    unsigned long long lm = ~0ULL;
#pragma unroll
    for (int j = 0; j < KSEL; ++j) lm = (pk[j] < lm) ? pk[j] : lm;
    unsigned long long gm = lm;
#pragma unroll
    for (int off = 1; off < 8; off <<= 1) {
      unsigned long long o = __shfl_xor(gm, off);
      gm = (o < gm) ? o : gm;
    }
    bool done = false;
#pragma unroll
    for (int j = 0; j < KSEL; ++j) if (!done && pk[j] == gm) { pk[j] = ~0ULL; done = true; }
    if (sp == 0) {
      cand_s[cbase + r] = __uint_as_float((unsigned int)(gm >> 32));
      cand_i[cbase + r] = (int)(unsigned int)(gm & 0xffffffffu);
    }
  }
}

// ---------------------------------------------------------------------------
// Finalize: per query, 256 threads (4 waves): 4-way parallel candidate merge
// 640 -> 4x16 -> top-16 (fp32 score, idx tie-break), fp64 rescore (4 cands
// per wave) -> exact top-8 order, softmax, parallel mask gather.
// ---------------------------------------------------------------------------
__global__ __launch_bounds__(256) void finalize_kernel(
    const float* __restrict__ Hq, const float* __restrict__ Hm,
    const float* __restrict__ masks,
    const float* __restrict__ cand_s, const int* __restrict__ cand_i,
    float* __restrict__ outW, float* __restrict__ outH)
{
  const int q    = blockIdx.x;
  const int t    = threadIdx.x;
  const int lane = t & 63;
  const int wave = t >> 6;

  __shared__ unsigned long long wtop[4][T16];
  __shared__ int    selIdx[T16];
  __shared__ double dArr[T16];
  __shared__ int    fin_i[KSEL];
  __shared__ double fin_d[KSEL];
  __shared__ double ew[KSEL];

  // phase 1: each wave takes 160 candidates -> its top-16 (indices unique)
  {
    const size_t base = (size_t)q * NC + (size_t)wave * (NC / 4);
    unsigned long long pk[3];
#pragma unroll
    for (int s = 0; s < 3; ++s) {
      const int c = lane + 64 * s;
      pk[s] = (c < NC / 4)
        ? ((((unsigned long long)__float_as_uint(cand_s[base + c])) << 32) | (unsigned int)cand_i[base + c])
        : ~0ULL;
    }
    for (int r = 0; r < T16; ++r) {
      unsigned long long lm = (pk[0] < pk[1]) ? pk[0] : pk[1];
      lm = (pk[2] < lm) ? pk[2] : lm;
      unsigned long long gm = lm;
#pragma unroll
      for (int off = 1; off < 64; off <<= 1) {
        unsigned long long o = __shfl_xor(gm, off);
        gm = (o < gm) ? o : gm;
      }
      bool done = false;
#pragma unroll
      for (int s = 0; s < 3; ++s) if (!done && pk[s] == gm) { pk[s] = ~0ULL; done = true; }
      if (lane == 0) wtop[wave][r] = gm;
    }
  }
  __syncthreads();

  // phase 2: wave 0 merges 64 -> global top-16
  if (wave == 0) {
    unsigned long long v = wtop[lane >> 4][lane & 15];
    for (int r = 0; r < T16; ++r) {
      unsigned long long gm = v;
#pragma unroll
      for (int off = 1; off < 64; off <<= 1) {
        unsigned long long o = __shfl_xor(gm, off);
        gm = (o < gm) ? o : gm;
      }
      if (v == gm) v = ~0ULL;
      if (lane == 0) selIdx[r] = (int)(unsigned int)(gm & 0xffffffffULL);
    }
  }
  __syncthreads();

  // phase 3: fp64 rescore, 4 candidates per wave
  const float4 q4 = *(const float4*)(Hq + (size_t)q * DIM + 4 * lane);
  double xp_ = (double)q4.x * q4.x + (double)q4.y * q4.y + (double)q4.z * q4.z + (double)q4.w * q4.w;
#pragma unroll
  for (int off = 1; off < 64; off <<= 1) xp_ += __shfl_xor(xp_, off);
  const double xsq = xp_;

  for (int r = wave; r < T16; r += 4) {
    const int cidx = selIdx[r];
    const float4 m4 = *(const float4*)(Hm + (size_t)cidx * DIM + 4 * lane);
    double dp = (double)q4.x * m4.x + (double)q4.y * m4.y + (double)q4.z * m4.z + (double)q4.w * m4.w;
    double yp = (double)m4.x * m4.x + (double)m4.y * m4.y + (double)m4.z * m4.z + (double)m4.w * m4.w;
#pragma unroll
    for (int off = 1; off < 64; off <<= 1) { dp += __shfl_xor(dp, off); yp += __shfl_xor(yp, off); }
    if (lane == 0) {
      double diff = xsq + yp - 2.0 * dp; if (diff < 0.0) diff = 0.0;
      double den = (1.0 - xsq) * (1.0 - yp);
      double arg = 1.0 + 2.0 * diff / (den + 1e-8);
      const double lo = 1.0 + 1e-6;
      if (arg < lo) arg = lo;
      dArr[r] = log(arg + sqrt(arg * arg - 1.0));   // arccosh
    }
  }
  __syncthreads();

  // phase 4: exact rank (dist, idx) -> top-8, softmax
  if (t < T16) {
    const double dj = dArr[t]; const int ij = selIdx[t];
    int rank = 0;
#pragma unroll
    for (int i = 0; i < T16; ++i)
      rank += (dArr[i] < dj || (dArr[i] == dj && selIdx[i] < ij)) ? 1 : 0;
    if (rank < KSEL) { fin_d[rank] = dj; fin_i[rank] = ij; }
  }
  __syncthreads();
  if (t < KSEL) ew[t] = exp(fin_d[0] - fin_d[t]);
  __syncthreads();
  if (t < KSEL) {
    double ssum = 0.0;
#pragma unroll
    for (int i = 0; i < KSEL; ++i) ssum += ew[i];
    outW[(size_t)q * KSEL + t] = (float)(ew[t] / ssum);
  }

  // phase 5: mask gather, 32 threads per output row
  const int g  = t >> 5;
  const int l0 = t & 31;
  const int row = fin_i[g];
  for (int l = l0; l < ATOMS; l += 32)
    outH[((size_t)q * KSEL + g) * ATOMS + l] = masks[(size_t)row * ATOMS + l];
}

// ---------------------------------------------------------------------------
extern "C" void kernel_launch(void* const* d_in, const int* in_sizes, int n_in,
                              void* d_out, int out_size, void* d_ws, size_t ws_size,
                              hipStream_t stream) {
  const float* Q     = (const float*)d_in[0];   // [1024,256]
  const float* M     = (const float*)d_in[1];   // [50000,256]
  const float* masks = (const float*)d_in[2];   // [50000,200]
  const float* W     = (const float*)d_in[3];   // [256,256]
  const float* bv    = (const float*)d_in[4];   // [256]
  // d_in[5] = k (always 8, hard-coded)

  char* w = (char*)d_ws;
  float*          Hq   = (float*)(w);                       //  1,048,576 B
  float*          Hm   = (float*)(w + 1048576);             // 51,200,000 B
  unsigned short* Hqb  = (unsigned short*)(w + 52248576);   //    524,288 B
  unsigned short* Hmb  = (unsigned short*)(w + 52772864);   // 25,624,576 B
  float2*         auxq = (float2*)(w + 78397440);           //      8,192 B
  float2*         auxm = (float2*)(w + 78405632);           //    400,384 B
  float*          cs   = (float*)(w + 78806016);            //  2,621,440 B
  int*            cix  = (int*)(w + 81427456);              //  2,621,440 B -> 84,048,896 total

  // Wt bf16 planes alias the cand_s region (dead until score_kernel writes it)
  unsigned short* Wt1 = (unsigned short*)(w + 78806016);    // 131,072 B
  unsigned short* Wt2 = Wt1 + DIM * DIM;
  unsigned short* Wt3 = Wt2 + DIM * DIM;

  wsplit_kernel<<<DIM, DIM, 0, stream>>>(W, Wt1, Wt2, Wt3);
  transform_kernel<<<B_Q / 16, 256, 0, stream>>>(Q, B_Q, Wt1, Wt2, Wt3, bv, Hq, Hqb, auxq);
  transform_kernel<<<N_M / 16, 256, 0, stream>>>(M, N_M, Wt1, Wt2, Wt3, bv, Hm, Hmb, auxm);
  score_kernel<<<dim3(NCHUNK, B_Q / 32), 256, 0, stream>>>(Hqb, Hmb, auxq, auxm, cs, cix);
  finalize_kernel<<<B_Q, 256, 0, stream>>>(Hq, Hm, masks, cs, cix,
                                           (float*)d_out, (float*)d_out + (size_t)B_Q * KSEL);
}

// Round 6
// 429.048 us; speedup vs baseline: 5.2815x; 1.1488x over previous
//
#include <hip/hip_runtime.h>
#include <hip/hip_bf16.h>
#include <math.h>
#include <float.h>

#define B_Q   1024
#define N_M   50000
#define DIM   256
#define ATOMS 200
#define KSEL  8
#define NCHUNK 40
#define CHUNK  1250       // N_M / NCHUNK exactly
#define MT    128
#define NMT   10          // CHUNK/MT rounded up
#define KTH   4           // per-thread top-K in scan
#define CPC   8           // candidates kept per (query, chunk)
#define NC    (NCHUNK * CPC)   // 320 candidates per query
#define T16   16          // finalize rescore set
#define AP    264         // A-plane LDS row stride in bf16 elems (528B, 16B-aligned)

typedef __attribute__((ext_vector_type(8))) short bf16x8;
typedef __attribute__((ext_vector_type(4))) float f32x4;

static __device__ inline unsigned short f2bf(float f) {
  __hip_bfloat16 h = __float2bfloat16(f);   // RNE
  return *reinterpret_cast<unsigned short*>(&h);
}

// 3-way bf16 Dekker split: x ~= s1+s2+s3, residual <= 2^-27 |x|
static __device__ inline void split3(float x, unsigned short& s1,
                                     unsigned short& s2, unsigned short& s3) {
  __hip_bfloat16 b1 = __float2bfloat16(x);
  float f1 = __bfloat162float(b1);
  float r1 = x - f1;
  __hip_bfloat16 b2 = __float2bfloat16(r1);
  float f2 = __bfloat162float(b2);
  __hip_bfloat16 b3 = __float2bfloat16(r1 - f2);
  s1 = *reinterpret_cast<unsigned short*>(&b1);
  s2 = *reinterpret_cast<unsigned short*>(&b2);
  s3 = *reinterpret_cast<unsigned short*>(&b3);
}

// fp32 tanh from fp64 pre-activation: arg scaled in fp64, HW v_exp_f32 (~1ulp),
// total rel err ~1.5e-7 — safe (4 passing rounds show rank gaps >> fp32 noise).
static __device__ inline float tanh32(double zd) {
  float tz = (float)(fabs(zd) * 2.8853900817779268147);  // 2|z|*log2(e)
  tz = fminf(tz, 120.f);
  const float E = __builtin_amdgcn_exp2f(tz);   // e^{2|z|} via v_exp_f32
  const float T = 1.f - 2.f / (E + 1.f);
  return (zd >= 0.0) ? T : -T;
}

// ---------------------------------------------------------------------------
// W pre-split: Wt planes [n][k] (transposed) as bf16 triple. 256x256, tiny.
// ---------------------------------------------------------------------------
__global__ __launch_bounds__(256) void wsplit_kernel(
    const float* __restrict__ W,
    unsigned short* __restrict__ Wt1, unsigned short* __restrict__ Wt2,
    unsigned short* __restrict__ Wt3)
{
  const int n = blockIdx.x;
  const int k = threadIdx.x;
  unsigned short s1, s2, s3;
  split3(W[(size_t)k * DIM + n], s1, s2, s3);
  Wt1[(size_t)n * DIM + k] = s1;
  Wt2[(size_t)n * DIM + k] = s2;
  Wt3[(size_t)n * DIM + k] = s3;
}

// ---------------------------------------------------------------------------
// Transform: H = to_poincare(X @ W + b); X@W via bf16 MFMA, 3-way Dekker split
// (6 product orders). Dominant x1*w1 term: C=0 per K=32 MFMA, drained to fp64
// each k-step. tanh in fp32 from the fp64 z (v_exp_f32). Norm/scale fp64.
// MFMA layouts (HW-verified on this GPU by score_kernel):
// A[m=lane&15][k=quad*8+j], B[n=lane&15][k=quad*8+j], D col=lane&15 row=quad*4+reg.
// Block = 16 rows x 256 cols; wave w owns col-tiles n0 = 64w + 16c.
// ---------------------------------------------------------------------------
__global__ __launch_bounds__(256) void transform_kernel(
    const float* __restrict__ X, int nrows,
    const unsigned short* __restrict__ Wt1, const unsigned short* __restrict__ Wt2,
    const unsigned short* __restrict__ Wt3, const float* __restrict__ bvec,
    float* __restrict__ H, unsigned short* __restrict__ Hb,
    float2* __restrict__ aux)
{
  __shared__ __align__(16) unsigned short X1s[16 * AP];
  __shared__ __align__(16) unsigned short X2s[16 * AP];
  __shared__ __align__(16) unsigned short X3s[16 * AP];
  __shared__ double red[4][16];

  const int t    = threadIdx.x;
  const int lane = t & 63;
  const int wave = t >> 6;
  const int row0 = blockIdx.x * 16;

  // stage + split X tile [16][256]
  {
    const int r  = t >> 4;
    const int c0 = (t & 15) * 16;
    const float4* src = (const float4*)(X + (size_t)(row0 + r) * DIM + c0);
#pragma unroll
    for (int v = 0; v < 4; ++v) {
      const float4 x4 = src[v];
      const float xv[4] = {x4.x, x4.y, x4.z, x4.w};
#pragma unroll
      for (int i = 0; i < 4; ++i) {
        unsigned short s1, s2, s3;
        split3(xv[i], s1, s2, s3);
        const int idx = r * AP + c0 + 4 * v + i;
        X1s[idx] = s1; X2s[idx] = s2; X3s[idx] = s3;
      }
    }
  }
  __syncthreads();

  const int lx   = lane & 15;    // A row m / B col n / D col
  const int quad = lane >> 4;    // k-group / D row-quad

  double d[4][4];
  f32x4 cacc[4];
#pragma unroll
  for (int c = 0; c < 4; ++c) {
#pragma unroll
    for (int r = 0; r < 4; ++r) d[c][r] = 0.0;
    cacc[c][0] = 0.f; cacc[c][1] = 0.f; cacc[c][2] = 0.f; cacc[c][3] = 0.f;
  }
  const f32x4 zero4 = {0.f, 0.f, 0.f, 0.f};

#pragma unroll
  for (int ks = 0; ks < 8; ++ks) {
    const int ko = ks * 32 + quad * 8;
    const bf16x8 a1 = *(const bf16x8*)(X1s + lx * AP + ko);
    const bf16x8 a2 = *(const bf16x8*)(X2s + lx * AP + ko);
    const bf16x8 a3 = *(const bf16x8*)(X3s + lx * AP + ko);
#pragma unroll
    for (int c = 0; c < 4; ++c) {
      const size_t nrow = (size_t)(wave * 64 + c * 16 + lx) * DIM + ko;
      const bf16x8 b1 = *(const bf16x8*)(Wt1 + nrow);
      const bf16x8 b2 = *(const bf16x8*)(Wt2 + nrow);
      const bf16x8 b3 = *(const bf16x8*)(Wt3 + nrow);
      const f32x4 mm = __builtin_amdgcn_mfma_f32_16x16x32_bf16(a1, b1, zero4, 0, 0, 0);
      cacc[c] = __builtin_amdgcn_mfma_f32_16x16x32_bf16(a1, b2, cacc[c], 0, 0, 0);
      cacc[c] = __builtin_amdgcn_mfma_f32_16x16x32_bf16(a2, b1, cacc[c], 0, 0, 0);
      cacc[c] = __builtin_amdgcn_mfma_f32_16x16x32_bf16(a1, b3, cacc[c], 0, 0, 0);
      cacc[c] = __builtin_amdgcn_mfma_f32_16x16x32_bf16(a2, b2, cacc[c], 0, 0, 0);
      cacc[c] = __builtin_amdgcn_mfma_f32_16x16x32_bf16(a3, b1, cacc[c], 0, 0, 0);
      d[c][0] += (double)mm[0]; d[c][1] += (double)mm[1];
      d[c][2] += (double)mm[2]; d[c][3] += (double)mm[3];
    }
  }

  // bias + tanh (fp32 from fp64 z): lane holds rows 4*quad+r, col wave*64+16c+lx
  float h[4][4];
#pragma unroll
  for (int c = 0; c < 4; ++c) {
    const double bb = (double)bvec[wave * 64 + 16 * c + lx];
#pragma unroll
    for (int r = 0; r < 4; ++r)
      h[c][r] = tanh32(d[c][r] + (double)cacc[c][r] + bb);
  }

  // row-norm: partial over this wave's 64 cols (fp64 accumulation of fp32 h)
  double p[4];
#pragma unroll
  for (int r = 0; r < 4; ++r) {
    p[r] = 0.0;
#pragma unroll
    for (int c = 0; c < 4; ++c) p[r] += (double)h[c][r] * (double)h[c][r];
  }
#pragma unroll
  for (int off = 1; off < 16; off <<= 1)
#pragma unroll
    for (int r = 0; r < 4; ++r) p[r] += __shfl_xor(p[r], off);
  if (lx == 0)
#pragma unroll
    for (int r = 0; r < 4; ++r) red[wave][4 * quad + r] = p[r];
  __syncthreads();

  double s[4];
#pragma unroll
  for (int r = 0; r < 4; ++r) {
    const int row = 4 * quad + r;
    const double nsq = red[0][row] + red[1][row] + red[2][row] + red[3][row];
    const double nrm = sqrt(nsq);
    s[r] = (nrm > 0.95) ? (0.95 / nrm) : 1.0;
  }
  __syncthreads();   // everyone done reading red before reuse

  float u[4][4];
  double py[4] = {0.0, 0.0, 0.0, 0.0};
#pragma unroll
  for (int c = 0; c < 4; ++c)
#pragma unroll
    for (int r = 0; r < 4; ++r) {
      u[c][r] = (float)((double)h[c][r] * s[r]);
      py[r] += (double)u[c][r] * (double)u[c][r];
    }
#pragma unroll
  for (int off = 1; off < 16; off <<= 1)
#pragma unroll
    for (int r = 0; r < 4; ++r) py[r] += __shfl_xor(py[r], off);
  if (lx == 0)
#pragma unroll
    for (int r = 0; r < 4; ++r) red[wave][4 * quad + r] = py[r];

  // stores (64B segments per quad)
#pragma unroll
  for (int c = 0; c < 4; ++c) {
    const int n = wave * 64 + 16 * c + lx;
#pragma unroll
    for (int r = 0; r < 4; ++r) {
      const size_t row = (size_t)(row0 + 4 * quad + r);
      H[row * DIM + n]  = u[c][r];
      Hb[row * DIM + n] = f2bf(u[c][r]);
    }
  }
  __syncthreads();
  if (t < 16) {
    const double ysq = red[0][t] + red[1][t] + red[2][t] + red[3][t];
    aux[row0 + t] = make_float2((float)ysq, (float)(1.0 / (1.0 - ysq)));
  }
}

// ---------------------------------------------------------------------------
// Score (MFMA): block = 32 queries x 1 chunk. Grid (chunk, qtile): linear id
// = c + 40*q -> XCD (id%8) = c%8, chunk's 640KB Hmb stays in one XCD's L2.
// Restructured K-loop (one vmcnt-preserving pipeline per mtile):
//   issue B loads -> scan prev scores (loads in flight) -> raw s_barrier ->
//   MFMA -> write scores -> raw lgkmcnt(0)+s_barrier.
// Raw barriers avoid the compiler's vmcnt(0) drain so prefetch survives.
// A-fragments live in LDS in fragment order (conflict-free b128 reads).
// Selection score s = max(xsq+ysq-2*dot,0)/(1-ysq): per-query monotone with
// the hyperbolic distance. Per-thread sorted top-4 over 1/8 of the chunk,
// 8-lane butterfly -> per-(query,chunk) top-8 candidates. (Safe: a global
// top-8 element has <=7 truly-better chunk-wide, so it survives chunk top-8;
// fp64 rescore in finalize fixes exact order.)
// ---------------------------------------------------------------------------
__global__ __launch_bounds__(256) void score_kernel(
    const unsigned short* __restrict__ Hqb, const unsigned short* __restrict__ Hmb,
    const float2* __restrict__ auxq, const float2* __restrict__ auxm,
    float* __restrict__ cand_s, int* __restrict__ cand_i)
{
  __shared__ float Sc[32 * 132];                           // 16896 B
  __shared__ __align__(16) unsigned short Afs[16 * 64 * 8]; // 16 KB, frag-order

  const int t    = threadIdx.x;
  const int lane = t & 63;
  const int wave = t >> 6;
  const int q0   = blockIdx.y * 32;
  const int c    = blockIdx.x;
  const int mbase = c * CHUNK;
  const int lx   = lane & 15;
  const int quad = lane >> 4;

  // stage A fragments into LDS (slot = ks*2+qs; each wave stages 4 slots)
#pragma unroll
  for (int i = 0; i < 4; ++i) {
    const int sl = wave * 4 + i;
    const int ks = sl >> 1, qs = sl & 1;
    const bf16x8 a = *(const bf16x8*)(Hqb + (size_t)(q0 + qs * 16 + lx) * DIM + ks * 32 + quad * 8);
    *(bf16x8*)(Afs + ((size_t)sl * 64 + lane) * 8) = a;
  }
  float xq[2][4];
#pragma unroll
  for (int qs = 0; qs < 2; ++qs)
#pragma unroll
    for (int r = 0; r < 4; ++r)
      xq[qs][r] = auxq[q0 + qs * 16 + quad * 4 + r].x;
  __syncthreads();

  // scan identity: 8 threads per query (contiguous lanes)
  const int sq = t >> 3;
  const int sp = t & 7;

  float topS[KTH]; int topI[KTH];   // sorted ascending; topS[3] = threshold
#pragma unroll
  for (int j = 0; j < KTH; ++j) { topS[j] = FLT_MAX; topI[j] = 0; }

  int prevGbase = 0, prevMlim = 0;

  for (int mt = 0; mt < NMT; ++mt) {
    const int mrow0 = mbase + mt * MT + wave * 32;
    // issue B loads (stay in flight across raw barriers)
    bf16x8 b0[8], b1[8];
#pragma unroll
    for (int ks = 0; ks < 8; ++ks) {
      b0[ks] = *(const bf16x8*)(Hmb + (size_t)(mrow0 + lx)      * DIM + ks * 32 + quad * 8);
      b1[ks] = *(const bf16x8*)(Hmb + (size_t)(mrow0 + 16 + lx) * DIM + ks * 32 + quad * 8);
    }
    const float2 aux0 = auxm[mrow0 + lx];
    const float2 aux1 = auxm[mrow0 + 16 + lx];

    // scan previous tile's scores while loads fly
    if (mt > 0) {
#pragma unroll
      for (int g = 0; g < 4; ++g) {
        const float4 v = *(const float4*)(&Sc[sq * 132 + sp * 16 + 4 * g]);
        const float vs[4] = {v.x, v.y, v.z, v.w};
#pragma unroll
        for (int e = 0; e < 4; ++e) {
          const int m = sp * 16 + 4 * g + e;
          const float sv = vs[e];
          if (m < prevMlim && sv < topS[3]) {
            topS[3] = sv; topI[3] = prevGbase + m;
            if (topS[3] < topS[2]) { float ts = topS[2]; topS[2] = topS[3]; topS[3] = ts;
                                     int ti = topI[2]; topI[2] = topI[3]; topI[3] = ti; }
            if (topS[2] < topS[1]) { float ts = topS[1]; topS[1] = topS[2]; topS[2] = ts;
                                     int ti = topI[1]; topI[1] = topI[2]; topI[2] = ti; }
            if (topS[1] < topS[0]) { float ts = topS[0]; topS[0] = topS[1]; topS[1] = ts;
                                     int ti = topI[0]; topI[0] = topI[1]; topI[1] = ti; }
          }
        }
      }
    }

    // separate scan reads (above) from this tile's Sc writes (below)
    __asm__ __volatile__("s_barrier" ::: "memory");

    f32x4 acc[2][2];
#pragma unroll
    for (int qs = 0; qs < 2; ++qs)
#pragma unroll
      for (int ms = 0; ms < 2; ++ms) { acc[qs][ms][0] = 0.f; acc[qs][ms][1] = 0.f;
                                       acc[qs][ms][2] = 0.f; acc[qs][ms][3] = 0.f; }
#pragma unroll
    for (int ks = 0; ks < 8; ++ks) {
      const bf16x8 a0 = *(const bf16x8*)(Afs + ((size_t)(ks * 2 + 0) * 64 + lane) * 8);
      const bf16x8 a1 = *(const bf16x8*)(Afs + ((size_t)(ks * 2 + 1) * 64 + lane) * 8);
      acc[0][0] = __builtin_amdgcn_mfma_f32_16x16x32_bf16(a0, b0[ks], acc[0][0], 0, 0, 0);
      acc[0][1] = __builtin_amdgcn_mfma_f32_16x16x32_bf16(a0, b1[ks], acc[0][1], 0, 0, 0);
      acc[1][0] = __builtin_amdgcn_mfma_f32_16x16x32_bf16(a1, b0[ks], acc[1][0], 0, 0, 0);
      acc[1][1] = __builtin_amdgcn_mfma_f32_16x16x32_bf16(a1, b1[ks], acc[1][1], 0, 0, 0);
    }

    // scores -> Sc
#pragma unroll
    for (int qs = 0; qs < 2; ++qs)
#pragma unroll
      for (int ms = 0; ms < 2; ++ms) {
        const float ym = ms ? aux1.x : aux0.x;
        const float ro = ms ? aux1.y : aux0.y;
        const int mcol = wave * 32 + ms * 16 + lx;
#pragma unroll
        for (int r = 0; r < 4; ++r) {
          const float sv = fmaxf(fmaf(-2.f, acc[qs][ms][r], xq[qs][r] + ym), 0.f) * ro;
          Sc[(qs * 16 + quad * 4 + r) * 132 + mcol] = sv;
        }
      }
    // make writes visible without draining vmcnt (prefetch stays in flight)
    __asm__ __volatile__("s_waitcnt lgkmcnt(0)\n\ts_barrier" ::: "memory");

    prevGbase = mbase + mt * MT;
    {
      const int rem = CHUNK - mt * MT;
      prevMlim = (rem < MT) ? rem : MT;
    }
  }

  // final tile scan
#pragma unroll
  for (int g = 0; g < 4; ++g) {
    const float4 v = *(const float4*)(&Sc[sq * 132 + sp * 16 + 4 * g]);
    const float vs[4] = {v.x, v.y, v.z, v.w};
#pragma unroll
    for (int e = 0; e < 4; ++e) {
      const int m = sp * 16 + 4 * g + e;
      const float sv = vs[e];
      if (m < prevMlim && sv < topS[3]) {
        topS[3] = sv; topI[3] = prevGbase + m;
        if (topS[3] < topS[2]) { float ts = topS[2]; topS[2] = topS[3]; topS[3] = ts;
                                 int ti = topI[2]; topI[2] = topI[3]; topI[3] = ti; }
        if (topS[2] < topS[1]) { float ts = topS[1]; topS[1] = topS[2]; topS[2] = ts;
                                 int ti = topI[1]; topI[1] = topI[2]; topI[2] = ti; }
        if (topS[1] < topS[0]) { float ts = topS[0]; topS[0] = topS[1]; topS[1] = ts;
                                 int ti = topI[0]; topI[0] = topI[1]; topI[1] = ti; }
      }
    }
  }

  // merge 8 threads x top-4 -> per-(query,chunk) top-8 (8-lane butterfly)
  unsigned long long pk[KTH];
#pragma unroll
  for (int j = 0; j < KTH; ++j)
    pk[j] = (((unsigned long long)__float_as_uint(topS[j])) << 32) | (unsigned int)topI[j];

  const size_t cbase = ((size_t)(q0 + sq) * NCHUNK + c) * CPC;
  for (int r = 0; r < CPC; ++r) {
    unsigned long long lm = (pk[0] < pk[1]) ? pk[0] : pk[1];
    unsigned long long l2 = (pk[2] < pk[3]) ? pk[2] : pk[3];
    lm = (l2 < lm) ? l2 : lm;
    unsigned long long gm = lm;
#pragma unroll
    for (int off = 1; off < 8; off <<= 1) {
      unsigned long long o = __shfl_xor(gm, off);
      gm = (o < gm) ? o : gm;
    }
    bool done = false;
#pragma unroll
    for (int j = 0; j < KTH; ++j) if (!done && pk[j] == gm) { pk[j] = ~0ULL; done = true; }
    if (sp == 0) {
      cand_s[cbase + r] = __uint_as_float((unsigned int)(gm >> 32));
      cand_i[cbase + r] = (int)(unsigned int)(gm & 0xffffffffu);
    }
  }
}

// ---------------------------------------------------------------------------
// Finalize: per query, 256 threads (4 waves): parallel candidate merge
// 320 -> 4x16 -> top-16 (fp32 score, idx tie-break), fp64 rescore (4 cands
// per wave) -> exact top-8 order, softmax, parallel mask gather.
// ---------------------------------------------------------------------------
__global__ __launch_bounds__(256) void finalize_kernel(
    const float* __restrict__ Hq, const float* __restrict__ Hm,
    const float* __restrict__ masks,
    const float* __restrict__ cand_s, const int* __restrict__ cand_i,
    float* __restrict__ outW, float* __restrict__ outH)
{
  const int q    = blockIdx.x;
  const int t    = threadIdx.x;
  const int lane = t & 63;
  const int wave = t >> 6;

  __shared__ unsigned long long wtop[4][T16];
  __shared__ int    selIdx[T16];
  __shared__ double dArr[T16];
  __shared__ int    fin_i[KSEL];
  __shared__ double fin_d[KSEL];
  __shared__ double ew[KSEL];

  // phase 1: each wave takes 80 candidates -> its top-16 (indices unique)
  {
    const size_t base = (size_t)q * NC + (size_t)wave * (NC / 4);
    unsigned long long pk[2];
#pragma unroll
    for (int s = 0; s < 2; ++s) {
      const int c = lane + 64 * s;
      pk[s] = (c < NC / 4)
        ? ((((unsigned long long)__float_as_uint(cand_s[base + c])) << 32) | (unsigned int)cand_i[base + c])
        : ~0ULL;
    }
    for (int r = 0; r < T16; ++r) {
      unsigned long long lm = (pk[0] < pk[1]) ? pk[0] : pk[1];
      unsigned long long gm = lm;
#pragma unroll
      for (int off = 1; off < 64; off <<= 1) {
        unsigned long long o = __shfl_xor(gm, off);
        gm = (o < gm) ? o : gm;
      }
      bool done = false;
#pragma unroll
      for (int s = 0; s < 2; ++s) if (!done && pk[s] == gm) { pk[s] = ~0ULL; done = true; }
      if (lane == 0) wtop[wave][r] = gm;
    }
  }
  __syncthreads();

  // phase 2: wave 0 merges 64 -> global top-16
  if (wave == 0) {
    unsigned long long v = wtop[lane >> 4][lane & 15];
    for (int r = 0; r < T16; ++r) {
      unsigned long long gm = v;
#pragma unroll
      for (int off = 1; off < 64; off <<= 1) {
        unsigned long long o = __shfl_xor(gm, off);
        gm = (o < gm) ? o : gm;
      }
      if (v == gm) v = ~0ULL;
      if (lane == 0) selIdx[r] = (int)(unsigned int)(gm & 0xffffffffULL);
    }
  }
  __syncthreads();

  // phase 3: fp64 rescore, 4 candidates per wave
  const float4 q4 = *(const float4*)(Hq + (size_t)q * DIM + 4 * lane);
  double xp_ = (double)q4.x * q4.x + (double)q4.y * q4.y + (double)q4.z * q4.z + (double)q4.w * q4.w;
#pragma unroll
  for (int off = 1; off < 64; off <<= 1) xp_ += __shfl_xor(xp_, off);
  const double xsq = xp_;

  for (int r = wave; r < T16; r += 4) {
    const int cidx = selIdx[r];
    const float4 m4 = *(const float4*)(Hm + (size_t)cidx * DIM + 4 * lane);
    double dp = (double)q4.x * m4.x + (double)q4.y * m4.y + (double)q4.z * m4.z + (double)q4.w * m4.w;
    double yp = (double)m4.x * m4.x + (double)m4.y * m4.y + (double)m4.z * m4.z + (double)m4.w * m4.w;
#pragma unroll
    for (int off = 1; off < 64; off <<= 1) { dp += __shfl_xor(dp, off); yp += __shfl_xor(yp, off); }
    if (lane == 0) {
      double diff = xsq + yp - 2.0 * dp; if (diff < 0.0) diff = 0.0;
      double den = (1.0 - xsq) * (1.0 - yp);
      double arg = 1.0 + 2.0 * diff / (den + 1e-8);
      const double lo = 1.0 + 1e-6;
      if (arg < lo) arg = lo;
      dArr[r] = log(arg + sqrt(arg * arg - 1.0));   // arccosh
    }
  }
  __syncthreads();

  // phase 4: exact rank (dist, idx) -> top-8, softmax
  if (t < T16) {
    const double dj = dArr[t]; const int ij = selIdx[t];
    int rank = 0;
#pragma unroll
    for (int i = 0; i < T16; ++i)
      rank += (dArr[i] < dj || (dArr[i] == dj && selIdx[i] < ij)) ? 1 : 0;
    if (rank < KSEL) { fin_d[rank] = dj; fin_i[rank] = ij; }
  }
  __syncthreads();
  if (t < KSEL) ew[t] = exp(fin_d[0] - fin_d[t]);
  __syncthreads();
  if (t < KSEL) {
    double ssum = 0.0;
#pragma unroll
    for (int i = 0; i < KSEL; ++i) ssum += ew[i];
    outW[(size_t)q * KSEL + t] = (float)(ew[t] / ssum);
  }

  // phase 5: mask gather, 32 threads per output row
  const int g  = t >> 5;
  const int l0 = t & 31;
  const int row = fin_i[g];
  for (int l = l0; l < ATOMS; l += 32)
    outH[((size_t)q * KSEL + g) * ATOMS + l] = masks[(size_t)row * ATOMS + l];
}

// ---------------------------------------------------------------------------
extern "C" void kernel_launch(void* const* d_in, const int* in_sizes, int n_in,
                              void* d_out, int out_size, void* d_ws, size_t ws_size,
                              hipStream_t stream) {
  const float* Q     = (const float*)d_in[0];   // [1024,256]
  const float* M     = (const float*)d_in[1];   // [50000,256]
  const float* masks = (const float*)d_in[2];   // [50000,200]
  const float* W     = (const float*)d_in[3];   // [256,256]
  const float* bv    = (const float*)d_in[4];   // [256]
  // d_in[5] = k (always 8, hard-coded)

  char* w = (char*)d_ws;
  float*          Hq   = (float*)(w);                       //  1,048,576 B
  float*          Hm   = (float*)(w + 1048576);             // 51,200,000 B
  unsigned short* Hqb  = (unsigned short*)(w + 52248576);   //    524,288 B
  unsigned short* Hmb  = (unsigned short*)(w + 52772864);   // 25,624,576 B (padded to 50048 rows)
  float2*         auxq = (float2*)(w + 78397440);           //      8,192 B
  float2*         auxm = (float2*)(w + 78405632);           //    400,384 B (padded)
  float*          cs   = (float*)(w + 78806016);            //  1,310,720 B
  int*            cix  = (int*)(w + 80116736);              //  1,310,720 B -> 81,427,456 total

  // Wt bf16 planes alias the cand_s region (dead until score_kernel writes it)
  unsigned short* Wt1 = (unsigned short*)(w + 78806016);    // 3 x 131,072 B
  unsigned short* Wt2 = Wt1 + DIM * DIM;
  unsigned short* Wt3 = Wt2 + DIM * DIM;

  wsplit_kernel<<<DIM, DIM, 0, stream>>>(W, Wt1, Wt2, Wt3);
  transform_kernel<<<B_Q / 16, 256, 0, stream>>>(Q, B_Q, Wt1, Wt2, Wt3, bv, Hq, Hqb, auxq);
  transform_kernel<<<N_M / 16, 256, 0, stream>>>(M, N_M, Wt1, Wt2, Wt3, bv, Hm, Hmb, auxm);
  score_kernel<<<dim3(NCHUNK, B_Q / 32), 256, 0, stream>>>(Hqb, Hmb, auxq, auxm, cs, cix);
  finalize_kernel<<<B_Q, 256, 0, stream>>>(Hq, Hm, masks, cs, cix,
                                           (float*)d_out, (float*)d_out + (size_t)B_Q * KSEL);
}

// Round 7
// 424.079 us; speedup vs baseline: 5.3434x; 1.0117x over previous
//
#include <hip/hip_runtime.h>
#include <hip/hip_bf16.h>
#include <math.h>
#include <float.h>

#define B_Q   1024
#define N_M   50000
#define DIM   256
#define ATOMS 200
#define KSEL  8
#define NCHUNK 40
#define CHUNK  1250       // N_M / NCHUNK exactly
#define MT    128
#define NMT   10          // CHUNK/MT rounded up
#define KTH   4           // per-thread top-K in scan
#define CPC   8           // candidates kept per (query, chunk)
#define NC    (NCHUNK * CPC)   // 320 candidates per query
#define T16   16          // finalize rescore set
#define AP    264         // A-plane LDS row stride in bf16 elems (528B, 16B-aligned)

typedef __attribute__((ext_vector_type(8))) short bf16x8;
typedef __attribute__((ext_vector_type(4))) float f32x4;

static __device__ inline unsigned short f2bf(float f) {
  __hip_bfloat16 h = __float2bfloat16(f);   // RNE
  return *reinterpret_cast<unsigned short*>(&h);
}

// 3-way bf16 Dekker split: x ~= s1+s2+s3, residual <= 2^-27 |x|
static __device__ inline void split3(float x, unsigned short& s1,
                                     unsigned short& s2, unsigned short& s3) {
  __hip_bfloat16 b1 = __float2bfloat16(x);
  float f1 = __bfloat162float(b1);
  float r1 = x - f1;
  __hip_bfloat16 b2 = __float2bfloat16(r1);
  float f2 = __bfloat162float(b2);
  __hip_bfloat16 b3 = __float2bfloat16(r1 - f2);
  s1 = *reinterpret_cast<unsigned short*>(&b1);
  s2 = *reinterpret_cast<unsigned short*>(&b2);
  s3 = *reinterpret_cast<unsigned short*>(&b3);
}

// fp32 tanh via HW v_exp_f32 (~1ulp): rel err ~1.5e-7.
// Error budget: z err 5e-7 -> u err 3e-7 -> dist err ~2e-5 << rank gaps ~1e-3.
static __device__ inline float tanh32(float z) {
  float tz = fabsf(z) * 2.885390082f;           // 2|z|*log2(e)
  tz = fminf(tz, 120.f);
  const float E = __builtin_amdgcn_exp2f(tz);   // e^{2|z|}
  const float T = 1.f - 2.f / (E + 1.f);
  return (z >= 0.f) ? T : -T;
}

// ---------------------------------------------------------------------------
// W pre-split: Wt planes [n][k] (transposed) as bf16 triple. 256x256, tiny.
// ---------------------------------------------------------------------------
__global__ __launch_bounds__(256) void wsplit_kernel(
    const float* __restrict__ W,
    unsigned short* __restrict__ Wt1, unsigned short* __restrict__ Wt2,
    unsigned short* __restrict__ Wt3)
{
  const int n = blockIdx.x;
  const int k = threadIdx.x;
  unsigned short s1, s2, s3;
  split3(W[(size_t)k * DIM + n], s1, s2, s3);
  Wt1[(size_t)n * DIM + k] = s1;
  Wt2[(size_t)n * DIM + k] = s2;
  Wt3[(size_t)n * DIM + k] = s3;
}

// ---------------------------------------------------------------------------
// Transform: H = to_poincare(X @ W + b); X@W via bf16 MFMA, 3-way Dekker split
// (6 product orders), ALL chained into one fp32 MFMA accumulator per n-tile:
// inner loop is pure MFMA + B-loads (no VALU, no fp64 drain). z err ~5e-7.
// Epilogue (tanh/norm/scale/aux) all-fp32 (err budget above). MFMA layouts
// (HW-verified on this GPU): A[m=lane&15][k=quad*8+j], B[n=lane&15][k=quad*8+j],
// D col=lane&15 row=quad*4+reg. Block = 16 rows x 256 cols; wave w owns
// col-tiles n0 = 64w + 16c. nrows multiple of 16.
// ---------------------------------------------------------------------------
__global__ __launch_bounds__(256) void transform_kernel(
    const float* __restrict__ X, int nrows,
    const unsigned short* __restrict__ Wt1, const unsigned short* __restrict__ Wt2,
    const unsigned short* __restrict__ Wt3, const float* __restrict__ bvec,
    float* __restrict__ H, unsigned short* __restrict__ Hb,
    float2* __restrict__ aux)
{
  __shared__ __align__(16) unsigned short X1s[16 * AP];
  __shared__ __align__(16) unsigned short X2s[16 * AP];
  __shared__ __align__(16) unsigned short X3s[16 * AP];
  __shared__ float red[4][16];

  const int t    = threadIdx.x;
  const int lane = t & 63;
  const int wave = t >> 6;
  const int row0 = blockIdx.x * 16;

  // stage + split X tile [16][256]
  {
    const int r  = t >> 4;
    const int c0 = (t & 15) * 16;
    const float4* src = (const float4*)(X + (size_t)(row0 + r) * DIM + c0);
#pragma unroll
    for (int v = 0; v < 4; ++v) {
      const float4 x4 = src[v];
      const float xv[4] = {x4.x, x4.y, x4.z, x4.w};
#pragma unroll
      for (int i = 0; i < 4; ++i) {
        unsigned short s1, s2, s3;
        split3(xv[i], s1, s2, s3);
        const int idx = r * AP + c0 + 4 * v + i;
        X1s[idx] = s1; X2s[idx] = s2; X3s[idx] = s3;
      }
    }
  }
  __syncthreads();

  const int lx   = lane & 15;    // A row m / B col n / D col
  const int quad = lane >> 4;    // k-group / D row-quad

  f32x4 cacc[4];
#pragma unroll
  for (int c = 0; c < 4; ++c) {
    cacc[c][0] = 0.f; cacc[c][1] = 0.f; cacc[c][2] = 0.f; cacc[c][3] = 0.f;
  }

#pragma unroll
  for (int ks = 0; ks < 8; ++ks) {
    const int ko = ks * 32 + quad * 8;
    const bf16x8 a1 = *(const bf16x8*)(X1s + lx * AP + ko);
    const bf16x8 a2 = *(const bf16x8*)(X2s + lx * AP + ko);
    const bf16x8 a3 = *(const bf16x8*)(X3s + lx * AP + ko);
#pragma unroll
    for (int c = 0; c < 4; ++c) {
      const size_t nrow = (size_t)(wave * 64 + c * 16 + lx) * DIM + ko;
      const bf16x8 b1 = *(const bf16x8*)(Wt1 + nrow);
      const bf16x8 b2 = *(const bf16x8*)(Wt2 + nrow);
      const bf16x8 b3 = *(const bf16x8*)(Wt3 + nrow);
      cacc[c] = __builtin_amdgcn_mfma_f32_16x16x32_bf16(a1, b1, cacc[c], 0, 0, 0);
      cacc[c] = __builtin_amdgcn_mfma_f32_16x16x32_bf16(a1, b2, cacc[c], 0, 0, 0);
      cacc[c] = __builtin_amdgcn_mfma_f32_16x16x32_bf16(a2, b1, cacc[c], 0, 0, 0);
      cacc[c] = __builtin_amdgcn_mfma_f32_16x16x32_bf16(a1, b3, cacc[c], 0, 0, 0);
      cacc[c] = __builtin_amdgcn_mfma_f32_16x16x32_bf16(a2, b2, cacc[c], 0, 0, 0);
      cacc[c] = __builtin_amdgcn_mfma_f32_16x16x32_bf16(a3, b1, cacc[c], 0, 0, 0);
    }
  }

  // bias + tanh (fp32): lane holds rows 4*quad+r, col wave*64+16c+lx
  float h[4][4];
#pragma unroll
  for (int c = 0; c < 4; ++c) {
    const float bb = bvec[wave * 64 + 16 * c + lx];
#pragma unroll
    for (int r = 0; r < 4; ++r)
      h[c][r] = tanh32(cacc[c][r] + bb);
  }

  // row-norm: partial over this wave's 64 cols, rows 4*quad+r (fp32)
  float p[4];
#pragma unroll
  for (int r = 0; r < 4; ++r)
    p[r] = h[0][r] * h[0][r] + h[1][r] * h[1][r] + h[2][r] * h[2][r] + h[3][r] * h[3][r];
#pragma unroll
  for (int off = 1; off < 16; off <<= 1)
#pragma unroll
    for (int r = 0; r < 4; ++r) p[r] += __shfl_xor(p[r], off);
  if (lx == 0)
#pragma unroll
    for (int r = 0; r < 4; ++r) red[wave][4 * quad + r] = p[r];
  __syncthreads();

  float s[4];
#pragma unroll
  for (int r = 0; r < 4; ++r) {
    const int row = 4 * quad + r;
    const float nsq = red[0][row] + red[1][row] + red[2][row] + red[3][row];
    const float nrm = sqrtf(nsq);
    s[r] = (nrm > 0.95f) ? (0.95f / nrm) : 1.f;
  }
  __syncthreads();   // everyone done reading red before reuse

  float u[4][4];
  float py[4] = {0.f, 0.f, 0.f, 0.f};
#pragma unroll
  for (int c = 0; c < 4; ++c)
#pragma unroll
    for (int r = 0; r < 4; ++r) {
      u[c][r] = h[c][r] * s[r];
      py[r] += u[c][r] * u[c][r];
    }
#pragma unroll
  for (int off = 1; off < 16; off <<= 1)
#pragma unroll
    for (int r = 0; r < 4; ++r) py[r] += __shfl_xor(py[r], off);
  if (lx == 0)
#pragma unroll
    for (int r = 0; r < 4; ++r) red[wave][4 * quad + r] = py[r];

  // stores (64B segments per quad)
#pragma unroll
  for (int c = 0; c < 4; ++c) {
    const int n = wave * 64 + 16 * c + lx;
#pragma unroll
    for (int r = 0; r < 4; ++r) {
      const size_t row = (size_t)(row0 + 4 * quad + r);
      H[row * DIM + n]  = u[c][r];
      Hb[row * DIM + n] = f2bf(u[c][r]);
    }
  }
  __syncthreads();
  if (t < 16) {
    const float ysq = red[0][t] + red[1][t] + red[2][t] + red[3][t];
    aux[row0 + t] = make_float2(ysq, 1.f / (1.f - ysq));
  }
}

// ---------------------------------------------------------------------------
// Score (MFMA): block = 32 queries x 1 chunk. Grid (chunk, qtile): linear id
// = c + 40*q -> XCD (id%8) = c%8, chunk's 640KB Hmb stays in one XCD's L2.
// Pipeline per mtile: issue B loads -> scan prev scores (loads in flight) ->
// raw s_barrier -> MFMA -> write scores -> raw lgkmcnt(0)+s_barrier.
// Raw barriers avoid the compiler's vmcnt(0) drain so prefetch survives.
// A-fragments in LDS fragment order (conflict-free b128 reads). Selection
// score s = max(xsq+ysq-2*dot,0)/(1-ysq) is per-query monotone with the
// hyperbolic distance. Per-thread sorted top-4, 8-lane butterfly ->
// per-(query,chunk) top-8 (global top-8 always survives chunk top-8;
// fp64 rescore in finalize fixes exact order).
// ---------------------------------------------------------------------------
__global__ __launch_bounds__(256) void score_kernel(
    const unsigned short* __restrict__ Hqb, const unsigned short* __restrict__ Hmb,
    const float2* __restrict__ auxq, const float2* __restrict__ auxm,
    float* __restrict__ cand_s, int* __restrict__ cand_i)
{
  __shared__ float Sc[32 * 132];                           // 16896 B
  __shared__ __align__(16) unsigned short Afs[16 * 64 * 8]; // 16 KB, frag-order

  const int t    = threadIdx.x;
  const int lane = t & 63;
  const int wave = t >> 6;
  const int q0   = blockIdx.y * 32;
  const int c    = blockIdx.x;
  const int mbase = c * CHUNK;
  const int lx   = lane & 15;
  const int quad = lane >> 4;

  // stage A fragments into LDS (slot = ks*2+qs; each wave stages 4 slots)
#pragma unroll
  for (int i = 0; i < 4; ++i) {
    const int sl = wave * 4 + i;
    const int ks = sl >> 1, qs = sl & 1;
    const bf16x8 a = *(const bf16x8*)(Hqb + (size_t)(q0 + qs * 16 + lx) * DIM + ks * 32 + quad * 8);
    *(bf16x8*)(Afs + ((size_t)sl * 64 + lane) * 8) = a;
  }
  float xq[2][4];
#pragma unroll
  for (int qs = 0; qs < 2; ++qs)
#pragma unroll
    for (int r = 0; r < 4; ++r)
      xq[qs][r] = auxq[q0 + qs * 16 + quad * 4 + r].x;
  __syncthreads();

  // scan identity: 8 threads per query (contiguous lanes)
  const int sq = t >> 3;
  const int sp = t & 7;

  float topS[KTH]; int topI[KTH];   // sorted ascending; topS[3] = threshold
#pragma unroll
  for (int j = 0; j < KTH; ++j) { topS[j] = FLT_MAX; topI[j] = 0; }

  int prevGbase = 0, prevMlim = 0;

  for (int mt = 0; mt < NMT; ++mt) {
    const int mrow0 = mbase + mt * MT + wave * 32;
    // issue B loads (stay in flight across raw barriers)
    bf16x8 b0[8], b1[8];
#pragma unroll
    for (int ks = 0; ks < 8; ++ks) {
      b0[ks] = *(const bf16x8*)(Hmb + (size_t)(mrow0 + lx)      * DIM + ks * 32 + quad * 8);
      b1[ks] = *(const bf16x8*)(Hmb + (size_t)(mrow0 + 16 + lx) * DIM + ks * 32 + quad * 8);
    }
    const float2 aux0 = auxm[mrow0 + lx];
    const float2 aux1 = auxm[mrow0 + 16 + lx];

    // scan previous tile's scores while loads fly
    if (mt > 0) {
#pragma unroll
      for (int g = 0; g < 4; ++g) {
        const float4 v = *(const float4*)(&Sc[sq * 132 + sp * 16 + 4 * g]);
        const float vs[4] = {v.x, v.y, v.z, v.w};
#pragma unroll
        for (int e = 0; e < 4; ++e) {
          const int m = sp * 16 + 4 * g + e;
          const float sv = vs[e];
          if (m < prevMlim && sv < topS[3]) {
            topS[3] = sv; topI[3] = prevGbase + m;
            if (topS[3] < topS[2]) { float ts = topS[2]; topS[2] = topS[3]; topS[3] = ts;
                                     int ti = topI[2]; topI[2] = topI[3]; topI[3] = ti; }
            if (topS[2] < topS[1]) { float ts = topS[1]; topS[1] = topS[2]; topS[2] = ts;
                                     int ti = topI[1]; topI[1] = topI[2]; topI[2] = ti; }
            if (topS[1] < topS[0]) { float ts = topS[0]; topS[0] = topS[1]; topS[1] = ts;
                                     int ti = topI[0]; topI[0] = topI[1]; topI[1] = ti; }
          }
        }
      }
    }

    // separate scan reads (above) from this tile's Sc writes (below)
    __asm__ __volatile__("s_barrier" ::: "memory");

    f32x4 acc[2][2];
#pragma unroll
    for (int qs = 0; qs < 2; ++qs)
#pragma unroll
      for (int ms = 0; ms < 2; ++ms) { acc[qs][ms][0] = 0.f; acc[qs][ms][1] = 0.f;
                                       acc[qs][ms][2] = 0.f; acc[qs][ms][3] = 0.f; }
#pragma unroll
    for (int ks = 0; ks < 8; ++ks) {
      const bf16x8 a0 = *(const bf16x8*)(Afs + ((size_t)(ks * 2 + 0) * 64 + lane) * 8);
      const bf16x8 a1 = *(const bf16x8*)(Afs + ((size_t)(ks * 2 + 1) * 64 + lane) * 8);
      acc[0][0] = __builtin_amdgcn_mfma_f32_16x16x32_bf16(a0, b0[ks], acc[0][0], 0, 0, 0);
      acc[0][1] = __builtin_amdgcn_mfma_f32_16x16x32_bf16(a0, b1[ks], acc[0][1], 0, 0, 0);
      acc[1][0] = __builtin_amdgcn_mfma_f32_16x16x32_bf16(a1, b0[ks], acc[1][0], 0, 0, 0);
      acc[1][1] = __builtin_amdgcn_mfma_f32_16x16x32_bf16(a1, b1[ks], acc[1][1], 0, 0, 0);
    }

    // scores -> Sc
#pragma unroll
    for (int qs = 0; qs < 2; ++qs)
#pragma unroll
      for (int ms = 0; ms < 2; ++ms) {
        const float ym = ms ? aux1.x : aux0.x;
        const float ro = ms ? aux1.y : aux0.y;
        const int mcol = wave * 32 + ms * 16 + lx;
#pragma unroll
        for (int r = 0; r < 4; ++r) {
          const float sv = fmaxf(fmaf(-2.f, acc[qs][ms][r], xq[qs][r] + ym), 0.f) * ro;
          Sc[(qs * 16 + quad * 4 + r) * 132 + mcol] = sv;
        }
      }
    // make writes visible without draining vmcnt (prefetch stays in flight)
    __asm__ __volatile__("s_waitcnt lgkmcnt(0)\n\ts_barrier" ::: "memory");

    prevGbase = mbase + mt * MT;
    {
      const int rem = CHUNK - mt * MT;
      prevMlim = (rem < MT) ? rem : MT;
    }
  }

  // final tile scan
#pragma unroll
  for (int g = 0; g < 4; ++g) {
    const float4 v = *(const float4*)(&Sc[sq * 132 + sp * 16 + 4 * g]);
    const float vs[4] = {v.x, v.y, v.z, v.w};
#pragma unroll
    for (int e = 0; e < 4; ++e) {
      const int m = sp * 16 + 4 * g + e;
      const float sv = vs[e];
      if (m < prevMlim && sv < topS[3]) {
        topS[3] = sv; topI[3] = prevGbase + m;
        if (topS[3] < topS[2]) { float ts = topS[2]; topS[2] = topS[3]; topS[3] = ts;
                                 int ti = topI[2]; topI[2] = topI[3]; topI[3] = ti; }
        if (topS[2] < topS[1]) { float ts = topS[1]; topS[1] = topS[2]; topS[2] = ts;
                                 int ti = topI[1]; topI[1] = topI[2]; topI[2] = ti; }
        if (topS[1] < topS[0]) { float ts = topS[0]; topS[0] = topS[1]; topS[1] = ts;
                                 int ti = topI[0]; topI[0] = topI[1]; topI[1] = ti; }
      }
    }
  }

  // merge 8 threads x top-4 -> per-(query,chunk) top-8 (8-lane butterfly)
  unsigned long long pk[KTH];
#pragma unroll
  for (int j = 0; j < KTH; ++j)
    pk[j] = (((unsigned long long)__float_as_uint(topS[j])) << 32) | (unsigned int)topI[j];

  const size_t cbase = ((size_t)(q0 + sq) * NCHUNK + c) * CPC;
  for (int r = 0; r < CPC; ++r) {
    unsigned long long lm = (pk[0] < pk[1]) ? pk[0] : pk[1];
    unsigned long long l2 = (pk[2] < pk[3]) ? pk[2] : pk[3];
    lm = (l2 < lm) ? l2 : lm;
    unsigned long long gm = lm;
#pragma unroll
    for (int off = 1; off < 8; off <<= 1) {
      unsigned long long o = __shfl_xor(gm, off);
      gm = (o < gm) ? o : gm;
    }
    bool done = false;
#pragma unroll
    for (int j = 0; j < KTH; ++j) if (!done && pk[j] == gm) { pk[j] = ~0ULL; done = true; }
    if (sp == 0) {
      cand_s[cbase + r] = __uint_as_float((unsigned int)(gm >> 32));
      cand_i[cbase + r] = (int)(unsigned int)(gm & 0xffffffffu);
    }
  }
}

// ---------------------------------------------------------------------------
// Finalize: per query, 256 threads (4 waves): parallel candidate merge
// 320 -> 4x16 -> top-16 (fp32 score, idx tie-break), fp64 rescore (4 cands
// per wave) -> exact top-8 order, softmax, parallel mask gather.
// ---------------------------------------------------------------------------
__global__ __launch_bounds__(256) void finalize_kernel(
    const float* __restrict__ Hq, const float* __restrict__ Hm,
    const float* __restrict__ masks,
    const float* __restrict__ cand_s, const int* __restrict__ cand_i,
    float* __restrict__ outW, float* __restrict__ outH)
{
  const int q    = blockIdx.x;
  const int t    = threadIdx.x;
  const int lane = t & 63;
  const int wave = t >> 6;

  __shared__ unsigned long long wtop[4][T16];
  __shared__ int    selIdx[T16];
  __shared__ double dArr[T16];
  __shared__ int    fin_i[KSEL];
  __shared__ double fin_d[KSEL];
  __shared__ double ew[KSEL];

  // phase 1: each wave takes 80 candidates -> its top-16 (indices unique)
  {
    const size_t base = (size_t)q * NC + (size_t)wave * (NC / 4);
    unsigned long long pk[2];
#pragma unroll
    for (int s = 0; s < 2; ++s) {
      const int c = lane + 64 * s;
      pk[s] = (c < NC / 4)
        ? ((((unsigned long long)__float_as_uint(cand_s[base + c])) << 32) | (unsigned int)cand_i[base + c])
        : ~0ULL;
    }
    for (int r = 0; r < T16; ++r) {
      unsigned long long lm = (pk[0] < pk[1]) ? pk[0] : pk[1];
      unsigned long long gm = lm;
#pragma unroll
      for (int off = 1; off < 64; off <<= 1) {
        unsigned long long o = __shfl_xor(gm, off);
        gm = (o < gm) ? o : gm;
      }
      bool done = false;
#pragma unroll
      for (int s = 0; s < 2; ++s) if (!done && pk[s] == gm) { pk[s] = ~0ULL; done = true; }
      if (lane == 0) wtop[wave][r] = gm;
    }
  }
  __syncthreads();

  // phase 2: wave 0 merges 64 -> global top-16
  if (wave == 0) {
    unsigned long long v = wtop[lane >> 4][lane & 15];
    for (int r = 0; r < T16; ++r) {
      unsigned long long gm = v;
#pragma unroll
      for (int off = 1; off < 64; off <<= 1) {
        unsigned long long o = __shfl_xor(gm, off);
        gm = (o < gm) ? o : gm;
      }
      if (v == gm) v = ~0ULL;
      if (lane == 0) selIdx[r] = (int)(unsigned int)(gm & 0xffffffffULL);
    }
  }
  __syncthreads();

  // phase 3: fp64 rescore, 4 candidates per wave
  const float4 q4 = *(const float4*)(Hq + (size_t)q * DIM + 4 * lane);
  double xp_ = (double)q4.x * q4.x + (double)q4.y * q4.y + (double)q4.z * q4.z + (double)q4.w * q4.w;
#pragma unroll
  for (int off = 1; off < 64; off <<= 1) xp_ += __shfl_xor(xp_, off);
  const double xsq = xp_;

  for (int r = wave; r < T16; r += 4) {
    const int cidx = selIdx[r];
    const float4 m4 = *(const float4*)(Hm + (size_t)cidx * DIM + 4 * lane);
    double dp = (double)q4.x * m4.x + (double)q4.y * m4.y + (double)q4.z * m4.z + (double)q4.w * m4.w;
    double yp = (double)m4.x * m4.x + (double)m4.y * m4.y + (double)m4.z * m4.z + (double)m4.w * m4.w;
#pragma unroll
    for (int off = 1; off < 64; off <<= 1) { dp += __shfl_xor(dp, off); yp += __shfl_xor(yp, off); }
    if (lane == 0) {
      double diff = xsq + yp - 2.0 * dp; if (diff < 0.0) diff = 0.0;
      double den = (1.0 - xsq) * (1.0 - yp);
      double arg = 1.0 + 2.0 * diff / (den + 1e-8);
      const double lo = 1.0 + 1e-6;
      if (arg < lo) arg = lo;
      dArr[r] = log(arg + sqrt(arg * arg - 1.0));   // arccosh
    }
  }
  __syncthreads();

  // phase 4: exact rank (dist, idx) -> top-8, softmax
  if (t < T16) {
    const double dj = dArr[t]; const int ij = selIdx[t];
    int rank = 0;
#pragma unroll
    for (int i = 0; i < T16; ++i)
      rank += (dArr[i] < dj || (dArr[i] == dj && selIdx[i] < ij)) ? 1 : 0;
    if (rank < KSEL) { fin_d[rank] = dj; fin_i[rank] = ij; }
  }
  __syncthreads();
  if (t < KSEL) ew[t] = exp(fin_d[0] - fin_d[t]);
  __syncthreads();
  if (t < KSEL) {
    double ssum = 0.0;
#pragma unroll
    for (int i = 0; i < KSEL; ++i) ssum += ew[i];
    outW[(size_t)q * KSEL + t] = (float)(ew[t] / ssum);
  }

  // phase 5: mask gather, 32 threads per output row
  const int g  = t >> 5;
  const int l0 = t & 31;
  const int row = fin_i[g];
  for (int l = l0; l < ATOMS; l += 32)
    outH[((size_t)q * KSEL + g) * ATOMS + l] = masks[(size_t)row * ATOMS + l];
}

// ---------------------------------------------------------------------------
extern "C" void kernel_launch(void* const* d_in, const int* in_sizes, int n_in,
                              void* d_out, int out_size, void* d_ws, size_t ws_size,
                              hipStream_t stream) {
  const float* Q     = (const float*)d_in[0];   // [1024,256]
  const float* M     = (const float*)d_in[1];   // [50000,256]
  const float* masks = (const float*)d_in[2];   // [50000,200]
  const float* W     = (const float*)d_in[3];   // [256,256]
  const float* bv    = (const float*)d_in[4];   // [256]
  // d_in[5] = k (always 8, hard-coded)

  char* w = (char*)d_ws;
  float*          Hq   = (float*)(w);                       //  1,048,576 B
  float*          Hm   = (float*)(w + 1048576);             // 51,200,000 B
  unsigned short* Hqb  = (unsigned short*)(w + 52248576);   //    524,288 B
  unsigned short* Hmb  = (unsigned short*)(w + 52772864);   // 25,624,576 B (padded to 50048 rows)
  float2*         auxq = (float2*)(w + 78397440);           //      8,192 B
  float2*         auxm = (float2*)(w + 78405632);           //    400,384 B (padded)
  float*          cs   = (float*)(w + 78806016);            //  1,310,720 B
  int*            cix  = (int*)(w + 80116736);              //  1,310,720 B -> 81,427,456 total

  // Wt bf16 planes alias the cand_s region (dead until score_kernel writes it)
  unsigned short* Wt1 = (unsigned short*)(w + 78806016);    // 3 x 131,072 B
  unsigned short* Wt2 = Wt1 + DIM * DIM;
  unsigned short* Wt3 = Wt2 + DIM * DIM;

  wsplit_kernel<<<DIM, DIM, 0, stream>>>(W, Wt1, Wt2, Wt3);
  transform_kernel<<<B_Q / 16, 256, 0, stream>>>(Q, B_Q, Wt1, Wt2, Wt3, bv, Hq, Hqb, auxq);
  transform_kernel<<<N_M / 16, 256, 0, stream>>>(M, N_M, Wt1, Wt2, Wt3, bv, Hm, Hmb, auxm);
  score_kernel<<<dim3(NCHUNK, B_Q / 32), 256, 0, stream>>>(Hqb, Hmb, auxq, auxm, cs, cix);
  finalize_kernel<<<B_Q, 256, 0, stream>>>(Hq, Hm, masks, cs, cix,
                                           (float*)d_out, (float*)d_out + (size_t)B_Q * KSEL);
}

// Round 8
// 368.960 us; speedup vs baseline: 6.1416x; 1.1494x over previous
//
#include <hip/hip_runtime.h>
#include <hip/hip_bf16.h>
#include <math.h>
#include <float.h>

#define B_Q   1024
#define N_M   50000
#define DIM   256
#define ATOMS 200
#define KSEL  8
#define NCHUNK 40
#define CHUNK  1250       // N_M / NCHUNK exactly
#define MT    128
#define NMT   10          // CHUNK/MT rounded up
#define KTH   4           // per-thread top-K in scan
#define CPC   8           // candidates kept per (query, chunk)
#define NC    (NCHUNK * CPC)   // 320 candidates per query
#define T16   16          // finalize rescore set
#define TROWS 64          // transform rows per block
#define APX   264         // A-plane LDS row stride in bf16 elems (528B, 16B-aligned)

typedef __attribute__((ext_vector_type(8))) short bf16x8;
typedef __attribute__((ext_vector_type(4))) float f32x4;

static __device__ inline unsigned short f2bf(float f) {
  __hip_bfloat16 h = __float2bfloat16(f);   // RNE
  return *reinterpret_cast<unsigned short*>(&h);
}

// RNE 3-way split (one-time W prep): x ~= s1+s2+s3, residual <= 2^-27 |x|
static __device__ inline void split3(float x, unsigned short& s1,
                                     unsigned short& s2, unsigned short& s3) {
  __hip_bfloat16 b1 = __float2bfloat16(x);
  float f1 = __bfloat162float(b1);
  float r1 = x - f1;
  __hip_bfloat16 b2 = __float2bfloat16(r1);
  float f2 = __bfloat162float(b2);
  __hip_bfloat16 b3 = __float2bfloat16(r1 - f2);
  s1 = *reinterpret_cast<unsigned short*>(&b1);
  s2 = *reinterpret_cast<unsigned short*>(&b2);
  s3 = *reinterpret_cast<unsigned short*>(&b3);
}

// Truncation 3-way split (hot path, 2 VALU/tier): residual <= 2^-24 |x|.
// x - trunc16(x) is exact (Sterbenz). Combined with RNE W tiers, dropped
// cross terms ~1e-7 rel — under the 5e-7 z-error budget.
static __device__ inline void split3t(float x, unsigned short& s1,
                                      unsigned short& s2, unsigned short& s3) {
  const unsigned u = __float_as_uint(x);
  s1 = (unsigned short)(u >> 16);
  const float f1 = __uint_as_float(u & 0xffff0000u);
  const float r1 = x - f1;                       // exact
  const unsigned v = __float_as_uint(r1);
  s2 = (unsigned short)(v >> 16);
  const float f2 = __uint_as_float(v & 0xffff0000u);
  const float r2 = r1 - f2;                      // exact
  s3 = (unsigned short)(__float_as_uint(r2) >> 16);
}

// fp32 tanh via HW v_exp_f32 (~1ulp): rel err ~1.5e-7.
static __device__ inline float tanh32(float z) {
  float tz = fabsf(z) * 2.885390082f;           // 2|z|*log2(e)
  tz = fminf(tz, 120.f);
  const float E = __builtin_amdgcn_exp2f(tz);   // e^{2|z|}
  const float T = 1.f - 2.f / (E + 1.f);
  return (z >= 0.f) ? T : -T;
}

// ---------------------------------------------------------------------------
// W pre-split: Wt planes [n][k] (transposed) as bf16 triple. 256x256, tiny.
// ---------------------------------------------------------------------------
__global__ __launch_bounds__(256) void wsplit_kernel(
    const float* __restrict__ W,
    unsigned short* __restrict__ Wt1, unsigned short* __restrict__ Wt2,
    unsigned short* __restrict__ Wt3)
{
  const int n = blockIdx.x;
  const int k = threadIdx.x;
  unsigned short s1, s2, s3;
  split3(W[(size_t)k * DIM + n], s1, s2, s3);
  Wt1[(size_t)n * DIM + k] = s1;
  Wt2[(size_t)n * DIM + k] = s2;
  Wt3[(size_t)n * DIM + k] = s3;
}

// ---------------------------------------------------------------------------
// Transform: H = to_poincare(X @ W + b); X@W via bf16 MFMA, 3-way Dekker
// split (6 product orders) chained into one fp32 accumulator per m-subtile.
// Block = 64 rows x 1024 threads (16 waves); wave w owns output cols
// [16w,16w+16): Wt is read ONCE per block (24 b128 loads/wave, explicit
// ks+1 double-buffer), A-planes staged in LDS (101KB, truncation splits,
// b128 writes). Per ks: 3 B-loads + 12 A ds_reads + 24 MFMA.
// MFMA layouts (HW-verified here through 4 passing rounds):
// A[m=lane&15][k=quad*8+j], B[n=lane&15][k=quad*8+j], D col=lane&15
// row=quad*4+reg. Epilogue fp32: tanh, 2-level row-norm reduce, scale, aux.
// ---------------------------------------------------------------------------
__global__ __launch_bounds__(1024) void transform_kernel(
    const float* __restrict__ X, int nrows,
    const unsigned short* __restrict__ Wt1, const unsigned short* __restrict__ Wt2,
    const unsigned short* __restrict__ Wt3, const float* __restrict__ bvec,
    float* __restrict__ H, unsigned short* __restrict__ Hb,
    float2* __restrict__ aux)
{
  __shared__ __align__(16) unsigned short X1s[TROWS * APX];
  __shared__ __align__(16) unsigned short X2s[TROWS * APX];
  __shared__ __align__(16) unsigned short X3s[TROWS * APX];
  __shared__ float red[16][TROWS];
  __shared__ float sArr[TROWS];

  const int t    = threadIdx.x;
  const int lane = t & 63;
  const int wave = t >> 6;
  const int row0 = blockIdx.x * TROWS;

  // stage + split X tile [64][256]: thread owns (row r, 16 cols at c0)
  {
    const int r  = t >> 4;
    const int c0 = (t & 15) * 16;
    int gr = row0 + r; if (gr >= nrows) gr = nrows - 1;   // clamp (stores guarded)
    const float4* src = (const float4*)(X + (size_t)gr * DIM + c0);
    bf16x8 p1[2], p2[2], p3[2];
#pragma unroll
    for (int half = 0; half < 2; ++half) {
#pragma unroll
      for (int v = 0; v < 2; ++v) {
        const float4 x4 = src[half * 2 + v];
        const float xv[4] = {x4.x, x4.y, x4.z, x4.w};
#pragma unroll
        for (int i = 0; i < 4; ++i) {
          unsigned short s1, s2, s3;
          split3t(xv[i], s1, s2, s3);
          p1[half][v * 4 + i] = (short)s1;
          p2[half][v * 4 + i] = (short)s2;
          p3[half][v * 4 + i] = (short)s3;
        }
      }
      *(bf16x8*)(X1s + r * APX + c0 + half * 8) = p1[half];
      *(bf16x8*)(X2s + r * APX + c0 + half * 8) = p2[half];
      *(bf16x8*)(X3s + r * APX + c0 + half * 8) = p3[half];
    }
  }
  __syncthreads();

  const int lx   = lane & 15;    // A row m / B col n / D col
  const int quad = lane >> 4;    // k-group / D row-quad
  const int n0   = wave * 16;    // this wave's output col-tile

  f32x4 acc[4];
#pragma unroll
  for (int ms = 0; ms < 4; ++ms) { acc[ms][0] = 0.f; acc[ms][1] = 0.f; acc[ms][2] = 0.f; acc[ms][3] = 0.f; }

  const size_t brow = (size_t)(n0 + lx) * DIM + quad * 8;
  bf16x8 b1c = *(const bf16x8*)(Wt1 + brow);
  bf16x8 b2c = *(const bf16x8*)(Wt2 + brow);
  bf16x8 b3c = *(const bf16x8*)(Wt3 + brow);

#pragma unroll
  for (int ks = 0; ks < 8; ++ks) {
    bf16x8 b1n, b2n, b3n;
    if (ks < 7) {                       // prefetch next k-step's B
      const size_t nb = brow + (ks + 1) * 32;
      b1n = *(const bf16x8*)(Wt1 + nb);
      b2n = *(const bf16x8*)(Wt2 + nb);
      b3n = *(const bf16x8*)(Wt3 + nb);
    }
    const int ko = ks * 32 + quad * 8;
#pragma unroll
    for (int ms = 0; ms < 4; ++ms) {
      const int ar = (ms * 16 + lx) * APX + ko;
      const bf16x8 a1 = *(const bf16x8*)(X1s + ar);
      const bf16x8 a2 = *(const bf16x8*)(X2s + ar);
      const bf16x8 a3 = *(const bf16x8*)(X3s + ar);
      acc[ms] = __builtin_amdgcn_mfma_f32_16x16x32_bf16(a1, b1c, acc[ms], 0, 0, 0);
      acc[ms] = __builtin_amdgcn_mfma_f32_16x16x32_bf16(a1, b2c, acc[ms], 0, 0, 0);
      acc[ms] = __builtin_amdgcn_mfma_f32_16x16x32_bf16(a2, b1c, acc[ms], 0, 0, 0);
      acc[ms] = __builtin_amdgcn_mfma_f32_16x16x32_bf16(a1, b3c, acc[ms], 0, 0, 0);
      acc[ms] = __builtin_amdgcn_mfma_f32_16x16x32_bf16(a2, b2c, acc[ms], 0, 0, 0);
      acc[ms] = __builtin_amdgcn_mfma_f32_16x16x32_bf16(a3, b1c, acc[ms], 0, 0, 0);
    }
    b1c = b1n; b2c = b2n; b3c = b3n;
  }

  // bias + tanh: lane holds rows ms*16+quad*4+r, col n0+lx (bias col-constant)
  const float bb = bvec[n0 + lx];
  float h[4][4];
#pragma unroll
  for (int ms = 0; ms < 4; ++ms)
#pragma unroll
    for (int r = 0; r < 4; ++r)
      h[ms][r] = tanh32(acc[ms][r] + bb);

  // row-norm partial over this wave's 16 cols (shuffle over lx)
  float p[4][4];
#pragma unroll
  for (int ms = 0; ms < 4; ++ms)
#pragma unroll
    for (int r = 0; r < 4; ++r) p[ms][r] = h[ms][r] * h[ms][r];
#pragma unroll
  for (int off = 1; off < 16; off <<= 1)
#pragma unroll
    for (int ms = 0; ms < 4; ++ms)
#pragma unroll
      for (int r = 0; r < 4; ++r) p[ms][r] += __shfl_xor(p[ms][r], off);
  if (lx == 0)
#pragma unroll
    for (int ms = 0; ms < 4; ++ms)
#pragma unroll
      for (int r = 0; r < 4; ++r) red[wave][ms * 16 + quad * 4 + r] = p[ms][r];
  __syncthreads();

  if (t < TROWS) {
    float nsq = 0.f;
#pragma unroll
    for (int w = 0; w < 16; ++w) nsq += red[w][t];
    const float nrm = sqrtf(nsq);
    sArr[t] = (nrm > 0.95f) ? (0.95f / nrm) : 1.f;
  }
  __syncthreads();

  float u[4][4];
#pragma unroll
  for (int ms = 0; ms < 4; ++ms)
#pragma unroll
    for (int r = 0; r < 4; ++r) {
      const float sc = sArr[ms * 16 + quad * 4 + r];
      u[ms][r] = h[ms][r] * sc;
      p[ms][r] = u[ms][r] * u[ms][r];
    }
#pragma unroll
  for (int off = 1; off < 16; off <<= 1)
#pragma unroll
    for (int ms = 0; ms < 4; ++ms)
#pragma unroll
      for (int r = 0; r < 4; ++r) p[ms][r] += __shfl_xor(p[ms][r], off);
  if (lx == 0)
#pragma unroll
    for (int ms = 0; ms < 4; ++ms)
#pragma unroll
      for (int r = 0; r < 4; ++r) red[wave][ms * 16 + quad * 4 + r] = p[ms][r];

  // stores: H fp32 + Hb bf16 (guarded rows)
#pragma unroll
  for (int ms = 0; ms < 4; ++ms)
#pragma unroll
    for (int r = 0; r < 4; ++r) {
      const int grow = row0 + ms * 16 + quad * 4 + r;
      if (grow < nrows) {
        H[(size_t)grow * DIM + n0 + lx]  = u[ms][r];
        Hb[(size_t)grow * DIM + n0 + lx] = f2bf(u[ms][r]);
      }
    }
  __syncthreads();
  if (t < TROWS) {
    const int grow = row0 + t;
    if (grow < nrows) {
      float ysq = 0.f;
#pragma unroll
      for (int w = 0; w < 16; ++w) ysq += red[w][t];
      aux[grow] = make_float2(ysq, 1.f / (1.f - ysq));
    }
  }
}

// ---------------------------------------------------------------------------
// Score (MFMA): block = 32 queries x 1 chunk. Grid (chunk, qtile): linear id
// = c + 40*q -> XCD (id%8) = c%8, chunk's 640KB Hmb stays in one XCD's L2.
// Pipeline per mtile: issue B loads -> scan prev scores (loads in flight) ->
// raw s_barrier -> MFMA -> write scores -> raw lgkmcnt(0)+s_barrier.
// Raw barriers avoid the compiler's vmcnt(0) drain so prefetch survives.
// A-fragments in LDS fragment order (conflict-free b128 reads). Selection
// score s = max(xsq+ysq-2*dot,0)/(1-ysq) is per-query monotone with the
// hyperbolic distance. Per-thread sorted top-4, 8-lane butterfly ->
// per-(query,chunk) top-8 (global top-8 always survives chunk top-8;
// fp64 rescore in finalize fixes exact order).
// ---------------------------------------------------------------------------
__global__ __launch_bounds__(256) void score_kernel(
    const unsigned short* __restrict__ Hqb, const unsigned short* __restrict__ Hmb,
    const float2* __restrict__ auxq, const float2* __restrict__ auxm,
    float* __restrict__ cand_s, int* __restrict__ cand_i)
{
  __shared__ float Sc[32 * 132];                           // 16896 B
  __shared__ __align__(16) unsigned short Afs[16 * 64 * 8]; // 16 KB, frag-order

  const int t    = threadIdx.x;
  const int lane = t & 63;
  const int wave = t >> 6;
  const int q0   = blockIdx.y * 32;
  const int c    = blockIdx.x;
  const int mbase = c * CHUNK;
  const int lx   = lane & 15;
  const int quad = lane >> 4;

  // stage A fragments into LDS (slot = ks*2+qs; each wave stages 4 slots)
#pragma unroll
  for (int i = 0; i < 4; ++i) {
    const int sl = wave * 4 + i;
    const int ks = sl >> 1, qs = sl & 1;
    const bf16x8 a = *(const bf16x8*)(Hqb + (size_t)(q0 + qs * 16 + lx) * DIM + ks * 32 + quad * 8);
    *(bf16x8*)(Afs + ((size_t)sl * 64 + lane) * 8) = a;
  }
  float xq[2][4];
#pragma unroll
  for (int qs = 0; qs < 2; ++qs)
#pragma unroll
    for (int r = 0; r < 4; ++r)
      xq[qs][r] = auxq[q0 + qs * 16 + quad * 4 + r].x;
  __syncthreads();

  // scan identity: 8 threads per query (contiguous lanes)
  const int sq = t >> 3;
  const int sp = t & 7;

  float topS[KTH]; int topI[KTH];   // sorted ascending; topS[3] = threshold
#pragma unroll
  for (int j = 0; j < KTH; ++j) { topS[j] = FLT_MAX; topI[j] = 0; }

  int prevGbase = 0, prevMlim = 0;

  for (int mt = 0; mt < NMT; ++mt) {
    const int mrow0 = mbase + mt * MT + wave * 32;
    // issue B loads (stay in flight across raw barriers)
    bf16x8 b0[8], b1[8];
#pragma unroll
    for (int ks = 0; ks < 8; ++ks) {
      b0[ks] = *(const bf16x8*)(Hmb + (size_t)(mrow0 + lx)      * DIM + ks * 32 + quad * 8);
      b1[ks] = *(const bf16x8*)(Hmb + (size_t)(mrow0 + 16 + lx) * DIM + ks * 32 + quad * 8);
    }
    const float2 aux0 = auxm[mrow0 + lx];
    const float2 aux1 = auxm[mrow0 + 16 + lx];

    // scan previous tile's scores while loads fly
    if (mt > 0) {
#pragma unroll
      for (int g = 0; g < 4; ++g) {
        const float4 v = *(const float4*)(&Sc[sq * 132 + sp * 16 + 4 * g]);
        const float vs[4] = {v.x, v.y, v.z, v.w};
#pragma unroll
        for (int e = 0; e < 4; ++e) {
          const int m = sp * 16 + 4 * g + e;
          const float sv = vs[e];
          if (m < prevMlim && sv < topS[3]) {
            topS[3] = sv; topI[3] = prevGbase + m;
            if (topS[3] < topS[2]) { float ts = topS[2]; topS[2] = topS[3]; topS[3] = ts;
                                     int ti = topI[2]; topI[2] = topI[3]; topI[3] = ti; }
            if (topS[2] < topS[1]) { float ts = topS[1]; topS[1] = topS[2]; topS[2] = ts;
                                     int ti = topI[1]; topI[1] = topI[2]; topI[2] = ti; }
            if (topS[1] < topS[0]) { float ts = topS[0]; topS[0] = topS[1]; topS[1] = ts;
                                     int ti = topI[0]; topI[0] = topI[1]; topI[1] = ti; }
          }
        }
      }
    }

    // separate scan reads (above) from this tile's Sc writes (below)
    __asm__ __volatile__("s_barrier" ::: "memory");

    f32x4 acc[2][2];
#pragma unroll
    for (int qs = 0; qs < 2; ++qs)
#pragma unroll
      for (int ms = 0; ms < 2; ++ms) { acc[qs][ms][0] = 0.f; acc[qs][ms][1] = 0.f;
                                       acc[qs][ms][2] = 0.f; acc[qs][ms][3] = 0.f; }
#pragma unroll
    for (int ks = 0; ks < 8; ++ks) {
      const bf16x8 a0 = *(const bf16x8*)(Afs + ((size_t)(ks * 2 + 0) * 64 + lane) * 8);
      const bf16x8 a1 = *(const bf16x8*)(Afs + ((size_t)(ks * 2 + 1) * 64 + lane) * 8);
      acc[0][0] = __builtin_amdgcn_mfma_f32_16x16x32_bf16(a0, b0[ks], acc[0][0], 0, 0, 0);
      acc[0][1] = __builtin_amdgcn_mfma_f32_16x16x32_bf16(a0, b1[ks], acc[0][1], 0, 0, 0);
      acc[1][0] = __builtin_amdgcn_mfma_f32_16x16x32_bf16(a1, b0[ks], acc[1][0], 0, 0, 0);
      acc[1][1] = __builtin_amdgcn_mfma_f32_16x16x32_bf16(a1, b1[ks], acc[1][1], 0, 0, 0);
    }

    // scores -> Sc
#pragma unroll
    for (int qs = 0; qs < 2; ++qs)
#pragma unroll
      for (int ms = 0; ms < 2; ++ms) {
        const float ym = ms ? aux1.x : aux0.x;
        const float ro = ms ? aux1.y : aux0.y;
        const int mcol = wave * 32 + ms * 16 + lx;
#pragma unroll
        for (int r = 0; r < 4; ++r) {
          const float sv = fmaxf(fmaf(-2.f, acc[qs][ms][r], xq[qs][r] + ym), 0.f) * ro;
          Sc[(qs * 16 + quad * 4 + r) * 132 + mcol] = sv;
        }
      }
    // make writes visible without draining vmcnt (prefetch stays in flight)
    __asm__ __volatile__("s_waitcnt lgkmcnt(0)\n\ts_barrier" ::: "memory");

    prevGbase = mbase + mt * MT;
    {
      const int rem = CHUNK - mt * MT;
      prevMlim = (rem < MT) ? rem : MT;
    }
  }

  // final tile scan
#pragma unroll
  for (int g = 0; g < 4; ++g) {
    const float4 v = *(const float4*)(&Sc[sq * 132 + sp * 16 + 4 * g]);
    const float vs[4] = {v.x, v.y, v.z, v.w};
#pragma unroll
    for (int e = 0; e < 4; ++e) {
      const int m = sp * 16 + 4 * g + e;
      const float sv = vs[e];
      if (m < prevMlim && sv < topS[3]) {
        topS[3] = sv; topI[3] = prevGbase + m;
        if (topS[3] < topS[2]) { float ts = topS[2]; topS[2] = topS[3]; topS[3] = ts;
                                 int ti = topI[2]; topI[2] = topI[3]; topI[3] = ti; }
        if (topS[2] < topS[1]) { float ts = topS[1]; topS[1] = topS[2]; topS[2] = ts;
                                 int ti = topI[1]; topI[1] = topI[2]; topI[2] = ti; }
        if (topS[1] < topS[0]) { float ts = topS[0]; topS[0] = topS[1]; topS[1] = ts;
                                 int ti = topI[0]; topI[0] = topI[1]; topI[1] = ti; }
      }
    }
  }

  // merge 8 threads x top-4 -> per-(query,chunk) top-8 (8-lane butterfly)
  unsigned long long pk[KTH];
#pragma unroll
  for (int j = 0; j < KTH; ++j)
    pk[j] = (((unsigned long long)__float_as_uint(topS[j])) << 32) | (unsigned int)topI[j];

  const size_t cbase = ((size_t)(q0 + sq) * NCHUNK + c) * CPC;
  for (int r = 0; r < CPC; ++r) {
    unsigned long long lm = (pk[0] < pk[1]) ? pk[0] : pk[1];
    unsigned long long l2 = (pk[2] < pk[3]) ? pk[2] : pk[3];
    lm = (l2 < lm) ? l2 : lm;
    unsigned long long gm = lm;
#pragma unroll
    for (int off = 1; off < 8; off <<= 1) {
      unsigned long long o = __shfl_xor(gm, off);
      gm = (o < gm) ? o : gm;
    }
    bool done = false;
#pragma unroll
    for (int j = 0; j < KTH; ++j) if (!done && pk[j] == gm) { pk[j] = ~0ULL; done = true; }
    if (sp == 0) {
      cand_s[cbase + r] = __uint_as_float((unsigned int)(gm >> 32));
      cand_i[cbase + r] = (int)(unsigned int)(gm & 0xffffffffu);
    }
  }
}

// ---------------------------------------------------------------------------
// Finalize: per query, 256 threads (4 waves): parallel candidate merge
// 320 -> 4x16 -> top-16 (fp32 score, idx tie-break), fp64 rescore (4 cands
// per wave) -> exact top-8 order, softmax, parallel mask gather.
// ---------------------------------------------------------------------------
__global__ __launch_bounds__(256) void finalize_kernel(
    const float* __restrict__ Hq, const float* __restrict__ Hm,
    const float* __restrict__ masks,
    const float* __restrict__ cand_s, const int* __restrict__ cand_i,
    float* __restrict__ outW, float* __restrict__ outH)
{
  const int q    = blockIdx.x;
  const int t    = threadIdx.x;
  const int lane = t & 63;
  const int wave = t >> 6;

  __shared__ unsigned long long wtop[4][T16];
  __shared__ int    selIdx[T16];
  __shared__ double dArr[T16];
  __shared__ int    fin_i[KSEL];
  __shared__ double fin_d[KSEL];
  __shared__ double ew[KSEL];

  // phase 1: each wave takes 80 candidates -> its top-16 (indices unique)
  {
    const size_t base = (size_t)q * NC + (size_t)wave * (NC / 4);
    unsigned long long pk[2];
#pragma unroll
    for (int s = 0; s < 2; ++s) {
      const int c = lane + 64 * s;
      pk[s] = (c < NC / 4)
        ? ((((unsigned long long)__float_as_uint(cand_s[base + c])) << 32) | (unsigned int)cand_i[base + c])
        : ~0ULL;
    }
    for (int r = 0; r < T16; ++r) {
      unsigned long long lm = (pk[0] < pk[1]) ? pk[0] : pk[1];
      unsigned long long gm = lm;
#pragma unroll
      for (int off = 1; off < 64; off <<= 1) {
        unsigned long long o = __shfl_xor(gm, off);
        gm = (o < gm) ? o : gm;
      }
      bool done = false;
#pragma unroll
      for (int s = 0; s < 2; ++s) if (!done && pk[s] == gm) { pk[s] = ~0ULL; done = true; }
      if (lane == 0) wtop[wave][r] = gm;
    }
  }
  __syncthreads();

  // phase 2: wave 0 merges 64 -> global top-16
  if (wave == 0) {
    unsigned long long v = wtop[lane >> 4][lane & 15];
    for (int r = 0; r < T16; ++r) {
      unsigned long long gm = v;
#pragma unroll
      for (int off = 1; off < 64; off <<= 1) {
        unsigned long long o = __shfl_xor(gm, off);
        gm = (o < gm) ? o : gm;
      }
      if (v == gm) v = ~0ULL;
      if (lane == 0) selIdx[r] = (int)(unsigned int)(gm & 0xffffffffULL);
    }
  }
  __syncthreads();

  // phase 3: fp64 rescore, 4 candidates per wave
  const float4 q4 = *(const float4*)(Hq + (size_t)q * DIM + 4 * lane);
  double xp_ = (double)q4.x * q4.x + (double)q4.y * q4.y + (double)q4.z * q4.z + (double)q4.w * q4.w;
#pragma unroll
  for (int off = 1; off < 64; off <<= 1) xp_ += __shfl_xor(xp_, off);
  const double xsq = xp_;

  for (int r = wave; r < T16; r += 4) {
    const int cidx = selIdx[r];
    const float4 m4 = *(const float4*)(Hm + (size_t)cidx * DIM + 4 * lane);
    double dp = (double)q4.x * m4.x + (double)q4.y * m4.y + (double)q4.z * m4.z + (double)q4.w * m4.w;
    double yp = (double)m4.x * m4.x + (double)m4.y * m4.y + (double)m4.z * m4.z + (double)m4.w * m4.w;
#pragma unroll
    for (int off = 1; off < 64; off <<= 1) { dp += __shfl_xor(dp, off); yp += __shfl_xor(yp, off); }
    if (lane == 0) {
      double diff = xsq + yp - 2.0 * dp; if (diff < 0.0) diff = 0.0;
      double den = (1.0 - xsq) * (1.0 - yp);
      double arg = 1.0 + 2.0 * diff / (den + 1e-8);
      const double lo = 1.0 + 1e-6;
      if (arg < lo) arg = lo;
      dArr[r] = log(arg + sqrt(arg * arg - 1.0));   // arccosh
    }
  }
  __syncthreads();

  // phase 4: exact rank (dist, idx) -> top-8, softmax
  if (t < T16) {
    const double dj = dArr[t]; const int ij = selIdx[t];
    int rank = 0;
#pragma unroll
    for (int i = 0; i < T16; ++i)
      rank += (dArr[i] < dj || (dArr[i] == dj && selIdx[i] < ij)) ? 1 : 0;
    if (rank < KSEL) { fin_d[rank] = dj; fin_i[rank] = ij; }
  }
  __syncthreads();
  if (t < KSEL) ew[t] = exp(fin_d[0] - fin_d[t]);
  __syncthreads();
  if (t < KSEL) {
    double ssum = 0.0;
#pragma unroll
    for (int i = 0; i < KSEL; ++i) ssum += ew[i];
    outW[(size_t)q * KSEL + t] = (float)(ew[t] / ssum);
  }

  // phase 5: mask gather, 32 threads per output row
  const int g  = t >> 5;
  const int l0 = t & 31;
  const int row = fin_i[g];
  for (int l = l0; l < ATOMS; l += 32)
    outH[((size_t)q * KSEL + g) * ATOMS + l] = masks[(size_t)row * ATOMS + l];
}

// ---------------------------------------------------------------------------
extern "C" void kernel_launch(void* const* d_in, const int* in_sizes, int n_in,
                              void* d_out, int out_size, void* d_ws, size_t ws_size,
                              hipStream_t stream) {
  const float* Q     = (const float*)d_in[0];   // [1024,256]
  const float* M     = (const float*)d_in[1];   // [50000,256]
  const float* masks = (const float*)d_in[2];   // [50000,200]
  const float* W     = (const float*)d_in[3];   // [256,256]
  const float* bv    = (const float*)d_in[4];   // [256]
  // d_in[5] = k (always 8, hard-coded)

  char* w = (char*)d_ws;
  float*          Hq   = (float*)(w);                       //  1,048,576 B
  float*          Hm   = (float*)(w + 1048576);             // 51,200,000 B
  unsigned short* Hqb  = (unsigned short*)(w + 52248576);   //    524,288 B
  unsigned short* Hmb  = (unsigned short*)(w + 52772864);   // 25,624,576 B (padded to 50048 rows)
  float2*         auxq = (float2*)(w + 78397440);           //      8,192 B
  float2*         auxm = (float2*)(w + 78405632);           //    400,384 B (padded)
  float*          cs   = (float*)(w + 78806016);            //  1,310,720 B
  int*            cix  = (int*)(w + 80116736);              //  1,310,720 B -> 81,427,456 total

  // Wt bf16 planes alias the cand_s region (dead until score_kernel writes it)
  unsigned short* Wt1 = (unsigned short*)(w + 78806016);    // 3 x 131,072 B
  unsigned short* Wt2 = Wt1 + DIM * DIM;
  unsigned short* Wt3 = Wt2 + DIM * DIM;

  wsplit_kernel<<<DIM, DIM, 0, stream>>>(W, Wt1, Wt2, Wt3);
  transform_kernel<<<(B_Q + TROWS - 1) / TROWS, 1024, 0, stream>>>(Q, B_Q, Wt1, Wt2, Wt3, bv, Hq, Hqb, auxq);
  transform_kernel<<<(N_M + TROWS - 1) / TROWS, 1024, 0, stream>>>(M, N_M, Wt1, Wt2, Wt3, bv, Hm, Hmb, auxm);
  score_kernel<<<dim3(NCHUNK, B_Q / 32), 256, 0, stream>>>(Hqb, Hmb, auxq, auxm, cs, cix);
  finalize_kernel<<<B_Q, 256, 0, stream>>>(Hq, Hm, masks, cs, cix,
                                           (float*)d_out, (float*)d_out + (size_t)B_Q * KSEL);
}